// Round 7
// baseline (267.734 us; speedup 1.0000x reference)
//
#include <hip/hip_runtime.h>
#include <hip/hip_bf16.h>
#include <math.h>

// B=8, S=4096, D_IN=64, H=512 single-head attention, fp32 I/O (dtype-probed).
// scores = x (Wq Wk^T) x^T / sqrt(H); out = softmax(scores) x Wv + bv.
// Folded biases: qb[s]=x_s·(Wq bk)+bq·bk, kb[t]=x_t·(Wk bq); +bv passes thru.
// R14 = R13 with portable sync primitives (__hip_atomic_fence doesn't exist
// on this ROCm): __threadfence() (agent-scope fence, emits L2 wb/inv on
// gfx94x+ -> handles cross-XCD non-coherence) + atomicAdd (device-scope by
// default, learn_hip m20). Pattern: 4 split blocks per 128-query group write
// partials; __syncthreads drains stores; tid0: threadfence (release) +
// atomicAdd(cnt); last block: threadfence (acquire), merges in fixed s-order
// (deterministic), normalizes, out-projects with mfma32. Main loop verbatim
// R12 (65us, refcheck'd). Fallbacks: 2-way split + separate combine, then
// R10 single-pass, by ws_size.

#define SS 4096
#define DD 64
#define HH 512

#define CSCALE ((float)(1.4426950408889634 * 0.04419417382415922))

typedef __bf16 bf16x8 __attribute__((ext_vector_type(8)));
typedef float  f32x4  __attribute__((ext_vector_type(4)));
typedef float  f32x16 __attribute__((ext_vector_type(16)));
typedef unsigned int u32x4 __attribute__((ext_vector_type(4)));

__device__ __forceinline__ float b2f(__hip_bfloat16 v) { return __bfloat162float(v); }

__device__ __forceinline__ f32x4 mfma16(bf16x8 a, bf16x8 b, f32x4 c) {
  return __builtin_amdgcn_mfma_f32_16x16x32_bf16(a, b, c, 0, 0, 0);
}
__device__ __forceinline__ f32x16 mfma32(bf16x8 a, bf16x8 b, f32x16 c) {
  return __builtin_amdgcn_mfma_f32_32x32x16_bf16(a, b, c, 0, 0, 0);
}

__device__ __forceinline__ unsigned pack2(float a, float b) {
  float2 f2; f2.x = a; f2.y = b;
  __hip_bfloat162 h2 = __float22bfloat162_rn(f2);   // a in low 16
  unsigned u; __builtin_memcpy(&u, &h2, 4);
  return u;
}

__device__ __forceinline__ float loadf(const void* p, size_t i, int isF32) {
  return isF32 ? ((const float*)p)[i] : b2f(((const __hip_bfloat16*)p)[i]);
}
__device__ __forceinline__ void load8f(const void* p, size_t i, int isF32, float* o) {
  if (isF32) {
    const float4 a = *(const float4*)((const float*)p + i);
    const float4 b = *(const float4*)((const float*)p + i + 4);
    o[0]=a.x; o[1]=a.y; o[2]=a.z; o[3]=a.w; o[4]=b.x; o[5]=b.y; o[6]=b.z; o[7]=b.w;
  } else {
    const bf16x8 v = *(const bf16x8*)((const __hip_bfloat16*)p + i);
#pragma unroll
    for (int k = 0; k < 8; ++k) { __hip_bfloat16 h; __builtin_memcpy(&h, ((const unsigned short*)&v) + k, 2); o[k] = b2f(h); }
  }
}

// ---------------- dtype probe (flag=1 -> fp32 inputs) ----------------------
__global__ void dtype_probe(const void* __restrict__ Wq, int* __restrict__ flag) {
  const unsigned short* h = (const unsigned short*)Wq;
  const int lane = threadIdx.x;
  unsigned int bits = ((unsigned int)h[lane * 2]) << 16;
  float v; __builtin_memcpy(&v, &bits, 4);
  v = fabsf(v);
  if (!isfinite(v) || v > 1e10f) v = 1e10f;
  for (int off = 1; off < 64; off <<= 1) v = fmaxf(v, __shfl_xor(v, off, 64));
  if (lane == 0) *flag = (v > 1e6f) ? 1 : 0;
}

// ---------------- prep: MT=(Wq Wk^T)^T bf16, u, w, c, wvT ------------------
__global__ __launch_bounds__(256) void prep_kernel(
    const void* __restrict__ Wq, const void* __restrict__ Wk,
    const void* __restrict__ Wv, const void* __restrict__ bq,
    const void* __restrict__ bk, __hip_bfloat16* __restrict__ MT,
    float* __restrict__ u, float* __restrict__ w_, float* __restrict__ c_,
    __hip_bfloat16* __restrict__ wvT, const int* __restrict__ flag) {
  const int t = threadIdx.x, blk = blockIdx.x;
  const int isF32 = *flag;
  if (blk < 64) {
    __shared__ float red[256];
    const int i = blk, j = t >> 2, part = t & 3;
    float acc = 0.f, aq[8], ak[8];
    for (int c = 0; c < 16; ++c) {
      load8f(Wq, (size_t)i * HH + part * 128 + c * 8, isF32, aq);
      load8f(Wk, (size_t)j * HH + part * 128 + c * 8, isF32, ak);
#pragma unroll
      for (int k = 0; k < 8; ++k) acc = fmaf(aq[k], ak[k], acc);
    }
    red[t] = acc;
    __syncthreads();
    if (t < 64)
      MT[t * 64 + i] = __float2bfloat16(red[t*4] + red[t*4+1] + red[t*4+2] + red[t*4+3]);
  } else if (blk == 64) {
    __shared__ float pu[256], pw[256], pc[64];
    const int i = t & 63, part = t >> 6;
    float au = 0.f, aw = 0.f, v1[8], v2[8];
    for (int c = 0; c < 16; ++c) {
      load8f(Wq, (size_t)i * HH + part * 128 + c * 8, isF32, v1);
      load8f(bk, part * 128 + c * 8, isF32, v2);
#pragma unroll
      for (int k = 0; k < 8; ++k) au = fmaf(v1[k], v2[k], au);
      load8f(Wk, (size_t)i * HH + part * 128 + c * 8, isF32, v1);
      load8f(bq, part * 128 + c * 8, isF32, v2);
#pragma unroll
      for (int k = 0; k < 8; ++k) aw = fmaf(v1[k], v2[k], aw);
    }
    pu[t] = au; pw[t] = aw;
    if (t < 64) {
      float s = 0.f;
      for (int e = 0; e < 8; ++e)
        s = fmaf(loadf(bq, t * 8 + e, isF32), loadf(bk, t * 8 + e, isF32), s);
      pc[t] = s;
    }
    __syncthreads();
    if (t < 64) {
      u[t]  = pu[t] + pu[t+64] + pu[t+128] + pu[t+192];
      w_[t] = pw[t] + pw[t+64] + pw[t+128] + pw[t+192];
    }
    if (t == 0) {
      float s = 0.f;
      for (int e = 0; e < 64; ++e) s += pc[e];
      *c_ = s;
    }
  } else {
    const int base = (blk - 65) * 2048 + t;
    for (int r = 0; r < 8; ++r) {
      const int e = base + r * 256;          // e = h*64 + d
      const int h = e >> 6, d = e & 63;
      wvT[e] = __float2bfloat16(loadf(Wv, (size_t)d * HH + h, isF32));
    }
  }
}

// ---------------- proj: xc, y = x*M (MFMA), qb/kb, xT; zero split counters -
__global__ __launch_bounds__(256) void proj_kernel(
    const void* __restrict__ xraw, const __hip_bfloat16* __restrict__ MT,
    const float* __restrict__ u, const float* __restrict__ w_,
    const float* __restrict__ c_, __hip_bfloat16* __restrict__ xc,
    __hip_bfloat16* __restrict__ y, float* __restrict__ qb,
    float* __restrict__ kb, __hip_bfloat16* __restrict__ xT,
    int* __restrict__ cnt, const int* __restrict__ flag) {
  __shared__ __hip_bfloat16 xs[64 * 72];
  __shared__ __hip_bfloat16 Ms[64 * 72];   // MT staged: Ms[ycol][d]
  __shared__ float us[64], wl[64];
  __shared__ float cs;

  const int t = threadIdx.x;
  const int isF32 = *flag;
  if (blockIdx.x == 0 && t < 256) cnt[t] = 0;   // split-combine counters
  {
    const int r = t >> 2, cb = (t & 3) * 16;
    *(bf16x8*)(&Ms[r * 72 + cb])     = *(const bf16x8*)(MT + r * 64 + cb);
    *(bf16x8*)(&Ms[r * 72 + cb + 8]) = *(const bf16x8*)(MT + r * 64 + cb + 8);
  }
  if (t < 64) { us[t] = u[t]; wl[t] = w_[t]; }
  if (t == 0) cs = *c_;

  const int b = blockIdx.x & 7;
  const int sbase = (blockIdx.x >> 3) * 64;
  const int rbase = b * SS + sbase;

  for (int i = 0; i < 2; ++i) {
    const int e = i * 256 + t;
    const int row = e >> 3, col = (e & 7) * 8;
    float v[8];
    load8f(xraw, (size_t)(rbase + row) * DD + col, isF32, v);
    __hip_bfloat16* dp = xs + row * 72 + col;
#pragma unroll
    for (int k = 0; k < 8; ++k) dp[k] = __float2bfloat16(v[k]);
  }
  __syncthreads();

  const int wv = t >> 6, lane = t & 63;
  const int l16 = lane & 15, quad = lane >> 4;
  // y tile: wave = 16 rows; A[m=row][k=d]
  const bf16x8 A0 = *(const bf16x8*)(&xs[(wv * 16 + l16) * 72 + quad * 8]);
  const bf16x8 A1 = *(const bf16x8*)(&xs[(wv * 16 + l16) * 72 + 32 + quad * 8]);
#pragma unroll
  for (int nt = 0; nt < 4; ++nt) {
    const bf16x8 B0 = *(const bf16x8*)(&Ms[(nt * 16 + l16) * 72 + quad * 8]);
    const bf16x8 B1 = *(const bf16x8*)(&Ms[(nt * 16 + l16) * 72 + 32 + quad * 8]);
    f32x4 C = (f32x4){0.f, 0.f, 0.f, 0.f};
    C = mfma16(A0, B0, C);
    C = mfma16(A1, B1, C);
#pragma unroll
    for (int r = 0; r < 4; ++r)
      y[(size_t)(rbase + wv * 16 + quad * 4 + r) * DD + nt * 16 + l16] =
          __float2bfloat16(C[r]);
  }
  if (t < 64) {
    float qa = 0.f, ka = 0.f;
    for (int d = 0; d < 64; ++d) {
      const float xv = b2f(xs[t * 72 + d]);
      qa = fmaf(xv, us[d], qa);
      ka = fmaf(xv, wl[d], ka);
    }
    qb[rbase + t] = (qa + cs) * CSCALE;
    kb[rbase + t] = ka * CSCALE;
  }
  for (int i = 0; i < 2; ++i) {
    const int e = i * 256 + t;
    const int row = e >> 3, col = (e & 7) * 8;
    *(bf16x8*)(xc + (size_t)(rbase + row) * DD + col) = *(const bf16x8*)(xs + row * 72 + col);
  }
  for (int i = 0; i < 16; ++i) {
    const int d = i * 4 + (t >> 6);
    const int sl = t & 63;
    xT[((size_t)b * DD + d) * SS + sbase + sl] = xs[sl * 72 + d];
  }
}

// ---------------- attn_split_fused: 4-way split + last-block combine -------
// grid 1024: b=blk&7 (XCD), ks=(blk>>3)&3, qg=blk>>5. Block = 128 queries.
// Main loop verbatim R12. Last sibling merges partials + out-projects.
__global__ __launch_bounds__(256) void attn_split_fused(
    const __hip_bfloat16* __restrict__ x,
    const __hip_bfloat16* __restrict__ y,
    const float* __restrict__ qb, const float* __restrict__ kb,
    const __hip_bfloat16* __restrict__ xT,
    float* __restrict__ Opart, float* __restrict__ lpart,
    int* __restrict__ cnt,
    const __hip_bfloat16* __restrict__ wvT, const void* __restrict__ bv_raw,
    void* __restrict__ out_raw, const int* __restrict__ flag) {
  __shared__ __hip_bfloat16 xs[2][32 * 72];    // 9.2 KB (X tile, tau-permuted)
  __shared__ __hip_bfloat16 vsm[2][64 * 40];   // 10.2 KB (V tile [d][key])
  __shared__ int lastflag;
  const int tid = threadIdx.x;
  const int wv = tid >> 6, lane = tid & 63;
  const int l32 = lane & 31, hi = lane >> 5;
  const int b = blockIdx.x & 7;
  const int ks = (blockIdx.x >> 3) & 3;
  const int qg = blockIdx.x >> 5;               // 0..31 within batch
  const int kspl = SS >> 2;                     // 1024
  const int koff = ks * kspl;
  const size_t rowq = ((size_t)b << 12) + ((size_t)(qg & 31)) * 128 + wv * 32;
  const size_t NP = (size_t)SS * 8;

  // Y frags (B-operand of S^T): lane needs Y[q=l32][d=16mi+8hi+j]
  bf16x8 Y[4];
#pragma unroll
  for (int mi = 0; mi < 4; ++mi)
    Y[mi] = *(const bf16x8*)(y + (rowq + l32) * DD + mi * 16 + hi * 8);
  const float qbl = qb[rowq + l32];

  // staging: key sxr -> LDS row tau(sxr); V: [d][key] rows of 40
  const int sxr = tid >> 3, sxc = (tid & 7) * 8;
  const int g = sxr >> 2;
  const int taur = (sxr & 3) + 4 * ((g & 4) | ((g & 1) << 1) | ((g >> 1) & 1));
  const int svd = tid >> 2, svc = (tid & 3) * 8;
  const __hip_bfloat16* gx = x + ((size_t)b * SS + koff + sxr) * DD + sxc;
  const __hip_bfloat16* gv = xT + ((size_t)b * DD + svd) * SS + koff + svc;
  const float* kbp = kb + (size_t)b * SS + koff + hi * 8;

  // prologue: tile 0 -> buf 0; tile 1 -> regs
  bf16x8 nx = *(const bf16x8*)gx;
  bf16x8 nv = *(const bf16x8*)gv;
  *(bf16x8*)(&xs[0][taur * 72 + sxc]) = nx;
  *(bf16x8*)(&vsm[0][svd * 40 + svc]) = nv;
  nx = *(const bf16x8*)(gx + 32 * DD);
  nv = *(const bf16x8*)(gv + 32);
  __syncthreads();

  f32x16 O0, O1;
#pragma unroll
  for (int r = 0; r < 16; ++r) { O0[r] = 0.f; O1[r] = 0.f; }
  float lp = 0.f;

  for (int kt = 0; kt < kspl; kt += 32) {
    const int p = (kt >> 5) & 1, np = p ^ 1;
    if (kt + 32 < kspl) {
      *(bf16x8*)(&xs[np][taur * 72 + sxc]) = nx;
      *(bf16x8*)(&vsm[np][svd * 40 + svc]) = nv;
      if (kt + 64 < kspl) {
        nx = *(const bf16x8*)(gx + (size_t)(kt + 64) * DD);
        nv = *(const bf16x8*)(gv + (kt + 64));
      }
    }
    // kb for this tile (L2): reg r <-> key 8hi+(r&7)+16(r>>3)
    const f32x4 kb0a = *(const f32x4*)(kbp + kt);
    const f32x4 kb0b = *(const f32x4*)(kbp + kt + 4);
    const f32x4 kb1a = *(const f32x4*)(kbp + kt + 16);
    const f32x4 kb1b = *(const f32x4*)(kbp + kt + 20);

    // X A-frags: row l32 (tau-permuted keys), cols 16mi+8hi+j
    const bf16x8 A0 = *(const bf16x8*)(&xs[p][l32 * 72 + hi * 8]);
    const bf16x8 A1 = *(const bf16x8*)(&xs[p][l32 * 72 + 16 + hi * 8]);
    const bf16x8 A2 = *(const bf16x8*)(&xs[p][l32 * 72 + 32 + hi * 8]);
    const bf16x8 A3 = *(const bf16x8*)(&xs[p][l32 * 72 + 48 + hi * 8]);

    f32x16 S;
#pragma unroll
    for (int r = 0; r < 16; ++r) S[r] = 0.f;
    S = mfma32(A0, Y[0], S);
    S = mfma32(A1, Y[1], S);
    S = mfma32(A2, Y[2], S);
    S = mfma32(A3, Y[3], S);

    float pv[16];
#pragma unroll
    for (int r = 0; r < 16; ++r) {
      const float kv = (r < 4) ? kb0a[r & 3]
                     : (r < 8) ? kb0b[r & 3]
                     : (r < 12) ? kb1a[r & 3] : kb1b[r & 3];
      pv[r] = __builtin_amdgcn_exp2f(fmaf(S[r], CSCALE, qbl + kv));
    }
    {
      float s0 = (pv[0]+pv[1]) + (pv[2]+pv[3]);
      float s1 = (pv[4]+pv[5]) + (pv[6]+pv[7]);
      float s2 = (pv[8]+pv[9]) + (pv[10]+pv[11]);
      float s3 = (pv[12]+pv[13]) + (pv[14]+pv[15]);
      lp += (s0 + s1) + (s2 + s3);
    }
    // PV A-frags: C-reg order IS operand order (tau construction)
    u32x4 R0, R1;
    R0[0] = pack2(pv[0], pv[1]);  R0[1] = pack2(pv[2], pv[3]);
    R0[2] = pack2(pv[4], pv[5]);  R0[3] = pack2(pv[6], pv[7]);
    R1[0] = pack2(pv[8], pv[9]);  R1[1] = pack2(pv[10], pv[11]);
    R1[2] = pack2(pv[12], pv[13]); R1[3] = pack2(pv[14], pv[15]);
    bf16x8 Pf0, Pf1;
    __builtin_memcpy(&Pf0, &R0, 16);
    __builtin_memcpy(&Pf1, &R1, 16);

    // V B-frags: col d = l32+32md, rows keys 16mk+8hi+j
    const bf16x8 V00 = *(const bf16x8*)(&vsm[p][l32 * 40 + hi * 8]);
    const bf16x8 V10 = *(const bf16x8*)(&vsm[p][l32 * 40 + 16 + hi * 8]);
    const bf16x8 V01 = *(const bf16x8*)(&vsm[p][(l32 + 32) * 40 + hi * 8]);
    const bf16x8 V11 = *(const bf16x8*)(&vsm[p][(l32 + 32) * 40 + 16 + hi * 8]);

    O0 = mfma32(Pf0, V00, O0);
    O0 = mfma32(Pf1, V10, O0);
    O1 = mfma32(Pf0, V01, O1);
    O1 = mfma32(Pf1, V11, O1);

    __syncthreads();
  }

  // merge l across hi halves (lane l and l^32 hold same query)
  lp += __shfl_xor(lp, 32, 64);
  if (hi == 0) lpart[(size_t)ks * NP + rowq + l32] = lp;

  // O partial write: lane = d-col (l32 + 32md), reg = query (r&3)+8(r>>2)+4hi
  float* Op = Opart + ((size_t)ks * NP + rowq) * 64;
#pragma unroll
  for (int r = 0; r < 16; ++r) {
    const int qrow = (r & 3) + 8 * (r >> 2) + 4 * hi;
    Op[(size_t)qrow * 64 + l32]      = O0[r];
    Op[(size_t)qrow * 64 + 32 + l32] = O1[r];
  }

  // ---- last-sibling combine (CK stream-k fixup pattern) ----
  __syncthreads();                          // drain partial stores (vmcnt 0)
  if (tid == 0) {
    __threadfence();                        // release: wb L2 (cross-XCD safe)
    const int gid = b * 32 + (int)(qg & 31);
    const int old = atomicAdd(&cnt[gid], 1);  // device-scope by default (m20)
    lastflag = (old == 3);
  }
  __syncthreads();
  if (!lastflag) return;
  __threadfence();                          // acquire: inv caches before read

  const int isF32 = *flag;
  // merged row-sum for this wave's 32 queries
  float lsum = 0.f;
#pragma unroll
  for (int s = 0; s < 4; ++s) lsum += lpart[(size_t)s * NP + rowq + l32];
  const float linv = (lsum > 0.f) ? 1.0f / lsum : 0.f;

  // merged+normalized P as mfma32 A-frags: lane (l32,hi), A[q=l32][d=16mi+8hi+j]
  bf16x8 PA[4];
  const float* Ob = Opart + rowq * 64;
#pragma unroll
  for (int mi = 0; mi < 4; ++mi) {
    const int dbase = mi * 16 + hi * 8;
    float acc[8];
#pragma unroll
    for (int j = 0; j < 8; ++j) acc[j] = 0.f;
#pragma unroll
    for (int s = 0; s < 4; ++s) {
      const float* pp = Ob + (size_t)s * NP * 64 + (size_t)l32 * 64 + dbase;
      const float4 a = *(const float4*)pp;
      const float4 c = *(const float4*)(pp + 4);
      acc[0] += a.x; acc[1] += a.y; acc[2] += a.z; acc[3] += a.w;
      acc[4] += c.x; acc[5] += c.y; acc[6] += c.z; acc[7] += c.w;
    }
    u32x4 R;
#pragma unroll
    for (int j = 0; j < 4; ++j)
      R[j] = pack2(acc[2*j] * linv, acc[2*j+1] * linv);
    __builtin_memcpy(&PA[mi], &R, 16);
  }

  // out-projection: out[32q x 512] = PA @ Wv + bv, 16 col-tiles of 32
  float* outf = (float*)out_raw;
  __hip_bfloat16* outb = (__hip_bfloat16*)out_raw;
  for (int nt = 0; nt < 16; ++nt) {
    const int h = nt * 32 + l32;
    f32x16 C;
#pragma unroll
    for (int r = 0; r < 16; ++r) C[r] = 0.f;
#pragma unroll
    for (int mi = 0; mi < 4; ++mi) {
      const bf16x8 Bf = *(const bf16x8*)(wvT + (size_t)h * DD + mi * 16 + hi * 8);
      C = mfma32(PA[mi], Bf, C);
    }
    const float bvv = loadf(bv_raw, h, isF32);
#pragma unroll
    for (int r = 0; r < 16; ++r) {
      const int qrow = (r & 3) + 8 * (r >> 2) + 4 * hi;
      const size_t oidx = (rowq + qrow) * HH + h;
      const float val = C[r] + bvv;
      if (isF32) outf[oidx] = val;
      else       outb[oidx] = __float2bfloat16(val);
    }
  }
}

// ---------------- attn_split: non-fused (2-way fallback) -------------------
__global__ __launch_bounds__(256) void attn_split(
    const __hip_bfloat16* __restrict__ x,
    const __hip_bfloat16* __restrict__ y,
    const float* __restrict__ qb, const float* __restrict__ kb,
    const __hip_bfloat16* __restrict__ xT,
    float* __restrict__ Opart, float* __restrict__ lpart, int lgs) {
  __shared__ __hip_bfloat16 xs[2][32 * 72];
  __shared__ __hip_bfloat16 vsm[2][64 * 40];
  const int tid = threadIdx.x;
  const int wv = tid >> 6, lane = tid & 63;
  const int l32 = lane & 31, hi = lane >> 5;
  const int b = blockIdx.x & 7;
  const int nspl = 1 << lgs;
  const int ks = (blockIdx.x >> 3) & (nspl - 1);
  const int qg = blockIdx.x >> (3 + lgs);
  const int kspl = SS >> lgs;
  const int koff = ks * kspl;
  const size_t rowq = ((size_t)b << 12) + (size_t)qg * 128 + wv * 32;

  bf16x8 Y[4];
#pragma unroll
  for (int mi = 0; mi < 4; ++mi)
    Y[mi] = *(const bf16x8*)(y + (rowq + l32) * DD + mi * 16 + hi * 8);
  const float qbl = qb[rowq + l32];

  const int sxr = tid >> 3, sxc = (tid & 7) * 8;
  const int g = sxr >> 2;
  const int taur = (sxr & 3) + 4 * ((g & 4) | ((g & 1) << 1) | ((g >> 1) & 1));
  const int svd = tid >> 2, svc = (tid & 3) * 8;
  const __hip_bfloat16* gx = x + ((size_t)b * SS + koff + sxr) * DD + sxc;
  const __hip_bfloat16* gv = xT + ((size_t)b * DD + svd) * SS + koff + svc;
  const float* kbp = kb + (size_t)b * SS + koff + hi * 8;

  bf16x8 nx = *(const bf16x8*)gx;
  bf16x8 nv = *(const bf16x8*)gv;
  *(bf16x8*)(&xs[0][taur * 72 + sxc]) = nx;
  *(bf16x8*)(&vsm[0][svd * 40 + svc]) = nv;
  nx = *(const bf16x8*)(gx + 32 * DD);
  nv = *(const bf16x8*)(gv + 32);
  __syncthreads();

  f32x16 O0, O1;
#pragma unroll
  for (int r = 0; r < 16; ++r) { O0[r] = 0.f; O1[r] = 0.f; }
  float lp = 0.f;

  for (int kt = 0; kt < kspl; kt += 32) {
    const int p = (kt >> 5) & 1, np = p ^ 1;
    if (kt + 32 < kspl) {
      *(bf16x8*)(&xs[np][taur * 72 + sxc]) = nx;
      *(bf16x8*)(&vsm[np][svd * 40 + svc]) = nv;
      if (kt + 64 < kspl) {
        nx = *(const bf16x8*)(gx + (size_t)(kt + 64) * DD);
        nv = *(const bf16x8*)(gv + (kt + 64));
      }
    }
    const f32x4 kb0a = *(const f32x4*)(kbp + kt);
    const f32x4 kb0b = *(const f32x4*)(kbp + kt + 4);
    const f32x4 kb1a = *(const f32x4*)(kbp + kt + 16);
    const f32x4 kb1b = *(const f32x4*)(kbp + kt + 20);

    const bf16x8 A0 = *(const bf16x8*)(&xs[p][l32 * 72 + hi * 8]);
    const bf16x8 A1 = *(const bf16x8*)(&xs[p][l32 * 72 + 16 + hi * 8]);
    const bf16x8 A2 = *(const bf16x8*)(&xs[p][l32 * 72 + 32 + hi * 8]);
    const bf16x8 A3 = *(const bf16x8*)(&xs[p][l32 * 72 + 48 + hi * 8]);

    f32x16 S;
#pragma unroll
    for (int r = 0; r < 16; ++r) S[r] = 0.f;
    S = mfma32(A0, Y[0], S);
    S = mfma32(A1, Y[1], S);
    S = mfma32(A2, Y[2], S);
    S = mfma32(A3, Y[3], S);

    float pv[16];
#pragma unroll
    for (int r = 0; r < 16; ++r) {
      const float kv = (r < 4) ? kb0a[r & 3]
                     : (r < 8) ? kb0b[r & 3]
                     : (r < 12) ? kb1a[r & 3] : kb1b[r & 3];
      pv[r] = __builtin_amdgcn_exp2f(fmaf(S[r], CSCALE, qbl + kv));
    }
    {
      float s0 = (pv[0]+pv[1]) + (pv[2]+pv[3]);
      float s1 = (pv[4]+pv[5]) + (pv[6]+pv[7]);
      float s2 = (pv[8]+pv[9]) + (pv[10]+pv[11]);
      float s3 = (pv[12]+pv[13]) + (pv[14]+pv[15]);
      lp += (s0 + s1) + (s2 + s3);
    }
    u32x4 R0, R1;
    R0[0] = pack2(pv[0], pv[1]);  R0[1] = pack2(pv[2], pv[3]);
    R0[2] = pack2(pv[4], pv[5]);  R0[3] = pack2(pv[6], pv[7]);
    R1[0] = pack2(pv[8], pv[9]);  R1[1] = pack2(pv[10], pv[11]);
    R1[2] = pack2(pv[12], pv[13]); R1[3] = pack2(pv[14], pv[15]);
    bf16x8 Pf0, Pf1;
    __builtin_memcpy(&Pf0, &R0, 16);
    __builtin_memcpy(&Pf1, &R1, 16);

    const bf16x8 V00 = *(const bf16x8*)(&vsm[p][l32 * 40 + hi * 8]);
    const bf16x8 V10 = *(const bf16x8*)(&vsm[p][l32 * 40 + 16 + hi * 8]);
    const bf16x8 V01 = *(const bf16x8*)(&vsm[p][(l32 + 32) * 40 + hi * 8]);
    const bf16x8 V11 = *(const bf16x8*)(&vsm[p][(l32 + 32) * 40 + 16 + hi * 8]);

    O0 = mfma32(Pf0, V00, O0);
    O0 = mfma32(Pf1, V10, O0);
    O1 = mfma32(Pf0, V01, O1);
    O1 = mfma32(Pf1, V11, O1);

    __syncthreads();
  }

  lp += __shfl_xor(lp, 32, 64);
  const size_t NP = (size_t)SS * 8;
  if (hi == 0) lpart[(size_t)ks * NP + rowq + l32] = lp;

  float* Op = Opart + ((size_t)ks * NP + rowq) * 64;
#pragma unroll
  for (int r = 0; r < 16; ++r) {
    const int qrow = (r & 3) + 8 * (r >> 2) + 4 * hi;
    Op[(size_t)qrow * 64 + l32]      = O0[r];
    Op[(size_t)qrow * 64 + 32 + l32] = O1[r];
  }
}

// ---------------- combine: separate-kernel fallback ------------------------
__global__ __launch_bounds__(128) void combine_kernel(
    const float* __restrict__ Opart, const float* __restrict__ lpart,
    const __hip_bfloat16* __restrict__ wvT, const void* __restrict__ bv_raw,
    void* __restrict__ out_raw, const int* __restrict__ flag, int nspl) {
  const int tid = threadIdx.x;
  const int wv = tid >> 6, lane = tid & 63;
  const int l16 = lane & 15, quad = lane >> 4;
  const size_t q0 = (size_t)blockIdx.x * 32 + (size_t)wv * 16;
  const int isF32 = *flag;
  const size_t NP = (size_t)SS * 8;

  float lsum = 0.f;
  for (int s = 0; s < nspl; ++s) lsum += lpart[(size_t)s * NP + q0 + l16];
  const float linv = (lsum > 0.f) ? 1.0f / lsum : 0.f;

  float vlo[8], vhi[8];
#pragma unroll
  for (int j = 0; j < 8; ++j) { vlo[j] = 0.f; vhi[j] = 0.f; }
  for (int s = 0; s < nspl; ++s) {
    const float* p0 = Opart + ((size_t)s * NP + q0 + l16) * 64 + quad * 8;
#pragma unroll
    for (int j = 0; j < 8; j += 4) {
      const float4 a = *(const float4*)(p0 + j);
      vlo[j]   += a.x; vlo[j+1] += a.y; vlo[j+2] += a.z; vlo[j+3] += a.w;
      const float4 c = *(const float4*)(p0 + 32 + j);
      vhi[j]   += c.x; vhi[j+1] += c.y; vhi[j+2] += c.z; vhi[j+3] += c.w;
    }
  }
  u32x4 Rlo, Rhi;
#pragma unroll
  for (int j = 0; j < 4; ++j) {
    Rlo[j] = pack2(vlo[2*j] * linv, vlo[2*j+1] * linv);
    Rhi[j] = pack2(vhi[2*j] * linv, vhi[2*j+1] * linv);
  }
  bf16x8 Alo, Ahi;
  __builtin_memcpy(&Alo, &Rlo, 16);
  __builtin_memcpy(&Ahi, &Rhi, 16);

  float* outf = (float*)out_raw;
  __hip_bfloat16* outb = (__hip_bfloat16*)out_raw;
#pragma unroll 4
  for (int ht = 0; ht < 32; ++ht) {
    const __hip_bfloat16* wp = wvT + (size_t)(ht * 16 + l16) * DD + quad * 8;
    const bf16x8 Wlo = *(const bf16x8*)wp;
    const bf16x8 Whi = *(const bf16x8*)(wp + 32);
    f32x4 C = (f32x4){0.f, 0.f, 0.f, 0.f};
    C = mfma16(Alo, Wlo, C);
    C = mfma16(Ahi, Whi, C);
    const float bvv = loadf(bv_raw, ht * 16 + l16, isF32);
#pragma unroll
    for (int r = 0; r < 4; ++r) {
      const size_t oidx = (q0 + quad * 4 + r) * HH + ht * 16 + l16;
      const float val = C[r] + bvv;
      if (isF32) outf[oidx] = val;
      else       outb[oidx] = __float2bfloat16(val);
    }
  }
}

// ---------------- attn: R10 fallback (single pass, used if ws too small) ---
__global__ __launch_bounds__(256) void attn_kernel(
    const __hip_bfloat16* __restrict__ x,
    const __hip_bfloat16* __restrict__ y,
    const float* __restrict__ qb, const float* __restrict__ kb,
    const __hip_bfloat16* __restrict__ xT,
    const __hip_bfloat16* __restrict__ wvT,
    const void* __restrict__ bv_raw,
    void* __restrict__ out_raw, const int* __restrict__ flag) {
  __shared__ __hip_bfloat16 xs[2][32 * 72];
  __shared__ __hip_bfloat16 vsm[2][64 * 40];
  __shared__ float kbl[SS];
  const int tid = threadIdx.x;
  const int wv = tid >> 6, lane = tid & 63;
  const int l16 = lane & 15, quad = lane >> 4;
  const int b = blockIdx.x & 7;
  const int qt = (blockIdx.x >> 3) * 4 + wv;
  const size_t rowq = ((size_t)b << 12) + ((size_t)qt << 4);
  const int isF32 = *flag;

  const __hip_bfloat16* xb  = x  + ((size_t)b * SS) * DD;
  const __hip_bfloat16* xTb = xT + ((size_t)b * DD) * SS;
  const float* kbb = kb + ((size_t)b * SS);

  const __hip_bfloat16* yp = y + (rowq + l16) * DD + quad * 8;
  const bf16x8 Ylo = *(const bf16x8*)yp;
  const bf16x8 Yhi = *(const bf16x8*)(yp + 32);
  const float qbl = qb[rowq + l16];

  const int sxr = tid >> 3, sxc = (tid & 7) * 8;
  const int taur = (sxr & 3) + ((sxr >> 3) << 2) + (((sxr >> 2) & 1) << 4);
  const int svd = tid >> 2, svc = (tid & 3) * 8;
  const __hip_bfloat16* gx = xb + (size_t)sxr * DD + sxc;
  const __hip_bfloat16* gv = xTb + (size_t)svd * SS + svc;

#pragma unroll
  for (int j = 0; j < 4; ++j) {
    const int c = j * 256 + tid;
    *(f32x4*)(&kbl[c * 4]) = *(const f32x4*)(kbb + c * 4);
  }

  bf16x8 nx = *(const bf16x8*)gx;
  bf16x8 nv = *(const bf16x8*)gv;
  *(bf16x8*)(&xs[0][taur * 72 + sxc]) = nx;
  *(bf16x8*)(&vsm[0][svd * 40 + svc]) = nv;
  nx = *(const bf16x8*)(gx + 32 * DD);
  nv = *(const bf16x8*)(gv + 32);
  __syncthreads();

  bf16x8 onesb;
#pragma unroll
  for (int j = 0; j < 8; ++j) onesb[j] = (__bf16)1.0f;

  f32x4 O[4];
#pragma unroll
  for (int n = 0; n < 4; ++n) O[n] = (f32x4){0.f, 0.f, 0.f, 0.f};
  f32x4 Ol = (f32x4){0.f, 0.f, 0.f, 0.f};

  for (int kt = 0; kt < SS; kt += 32) {
    const int p = (kt >> 5) & 1, np = p ^ 1;
    if (kt + 32 < SS) {
      *(bf16x8*)(&xs[np][taur * 72 + sxc]) = nx;
      *(bf16x8*)(&vsm[np][svd * 40 + svc]) = nv;
      if (kt + 64 < SS) {
        nx = *(const bf16x8*)(gx + (size_t)(kt + 64) * DD);
        nv = *(const bf16x8*)(gv + (kt + 64));
      }
    }
    const bf16x8 B00 = *(const bf16x8*)(&xs[p][l16 * 72 + quad * 8]);
    const bf16x8 B01 = *(const bf16x8*)(&xs[p][l16 * 72 + 32 + quad * 8]);
    const bf16x8 B10 = *(const bf16x8*)(&xs[p][(16 + l16) * 72 + quad * 8]);
    const bf16x8 B11 = *(const bf16x8*)(&xs[p][(16 + l16) * 72 + 32 + quad * 8]);
    const bf16x8 V0 = *(const bf16x8*)(&vsm[p][l16 * 40 + quad * 8]);
    const bf16x8 V1 = *(const bf16x8*)(&vsm[p][(16 + l16) * 40 + quad * 8]);
    const bf16x8 V2 = *(const bf16x8*)(&vsm[p][(32 + l16) * 40 + quad * 8]);
    const bf16x8 V3 = *(const bf16x8*)(&vsm[p][(48 + l16) * 40 + quad * 8]);

    f32x4 S0 = (f32x4){0.f, 0.f, 0.f, 0.f};
    f32x4 S1 = (f32x4){0.f, 0.f, 0.f, 0.f};
    S0 = mfma16(B00, Ylo, S0);
    S0 = mfma16(B01, Yhi, S0);
    S1 = mfma16(B10, Ylo, S1);
    S1 = mfma16(B11, Yhi, S1);

    const f32x4 kb0 = *(const f32x4*)(&kbl[kt + quad * 8]);
    const f32x4 kb1 = *(const f32x4*)(&kbl[kt + quad * 8 + 4]);

    float p0[4], p1[4];
#pragma unroll
    for (int r = 0; r < 4; ++r) {
      p0[r] = __builtin_amdgcn_exp2f(fmaf(S0[r], CSCALE, qbl + kb0[r]));
      p1[r] = __builtin_amdgcn_exp2f(fmaf(S1[r], CSCALE, qbl + kb1[r]));
    }
    u32x4 R;
    R[0] = pack2(p0[0], p0[1]);
    R[1] = pack2(p0[2], p0[3]);
    R[2] = pack2(p1[0], p1[1]);
    R[3] = pack2(p1[2], p1[3]);
    bf16x8 Pf;
    __builtin_memcpy(&Pf, &R, 16);

    O[0] = mfma16(Pf, V0, O[0]);
    O[1] = mfma16(Pf, V1, O[1]);
    O[2] = mfma16(Pf, V2, O[2]);
    O[3] = mfma16(Pf, V3, O[3]);
    Ol = mfma16(Pf, onesb, Ol);

    __syncthreads();
  }

  float inv_l[4];
#pragma unroll
  for (int r = 0; r < 4; ++r)
    inv_l[r] = (Ol[r] > 0.f) ? 1.0f / Ol[r] : 0.f;
  __hip_bfloat16* pl = &xs[0][0] + wv * 1152;
#pragma unroll
  for (int n = 0; n < 4; ++n)
#pragma unroll
    for (int r = 0; r < 4; ++r) {
      const int row = quad * 4 + r;
      pl[row * 72 + n * 16 + l16] = __float2bfloat16(O[n][r] * inv_l[r]);
    }
  __syncthreads();
  const bf16x8 Alo = *(const bf16x8*)(pl + l16 * 72 + quad * 8);
  const bf16x8 Ahi = *(const bf16x8*)(pl + l16 * 72 + 32 + quad * 8);

  float* outf = (float*)out_raw;
  __hip_bfloat16* outb = (__hip_bfloat16*)out_raw;
#pragma unroll 4
  for (int ht = 0; ht < 32; ++ht) {
    const __hip_bfloat16* wp = wvT + (size_t)(ht * 16 + l16) * DD + quad * 8;
    const bf16x8 Wlo = *(const bf16x8*)wp;
    const bf16x8 Whi = *(const bf16x8*)(wp + 32);
    f32x4 C = (f32x4){0.f, 0.f, 0.f, 0.f};
    C = mfma16(Alo, Wlo, C);
    C = mfma16(Ahi, Whi, C);
    const float bvv = loadf(bv_raw, ht * 16 + l16, isF32);
#pragma unroll
    for (int r = 0; r < 4; ++r) {
      const size_t oidx = (rowq + quad * 4 + r) * HH + ht * 16 + l16;
      const float val = C[r] + bvv;
      if (isF32) outf[oidx] = val;
      else       outb[oidx] = __float2bfloat16(val);
    }
  }
}

// ---------------- launcher --------------------------------------------------
extern "C" void kernel_launch(void* const* d_in, const int* in_sizes, int n_in,
                              void* d_out, int out_size, void* d_ws,
                              size_t ws_size, hipStream_t stream) {
  char* ws = (char*)d_ws;
  int*   flag = (int*)(ws + 0);
  __hip_bfloat16* MT = (__hip_bfloat16*)(ws + 1024);       // 8 KB
  float* u    = (float*)(ws + 9216);
  float* w_   = (float*)(ws + 9728);
  float* c_   = (float*)(ws + 10240);
  int*   cnt  = (int*)(ws + 12288);                         // 1 KB (256 ints)
  __hip_bfloat16* wvT = (__hip_bfloat16*)(ws + 32768);     // 64 KB
  __hip_bfloat16* xc  = (__hip_bfloat16*)(ws + 131072);    // 4 MB
  __hip_bfloat16* y   = (__hip_bfloat16*)(ws + 4325376);   // 4 MB
  float* qb = (float*)(ws + 8519680);                       // 128 KB
  float* kb = (float*)(ws + 8650752);                       // 128 KB
  __hip_bfloat16* xT = (__hip_bfloat16*)(ws + 8781824);    // 4 MB
  float* Opart = (float*)(ws + 16777216);                   // up to 32 MB
  const size_t NP = (size_t)SS * 8;
  const size_t need4 = 16777216UL + 4UL * NP * 64 * 4 + 4UL * NP * 4;  // ~50.9 MB
  const size_t need2 = 16777216UL + 2UL * NP * 64 * 4 + 2UL * NP * 4;  // ~33.8 MB

  dtype_probe<<<1, 64, 0, stream>>>(d_in[1], flag);
  prep_kernel<<<81, 256, 0, stream>>>(d_in[1], d_in[3], d_in[5], d_in[2],
                                      d_in[4], MT, u, w_, c_, wvT, flag);
  proj_kernel<<<512, 256, 0, stream>>>(d_in[0], MT, u, w_, c_, xc, y, qb, kb,
                                       xT, cnt, flag);
  if (ws_size >= need4) {
    float* lpart = (float*)(ws + 16777216 + 4UL * NP * 64 * 4);
    attn_split_fused<<<1024, 256, 0, stream>>>(xc, y, qb, kb, xT, Opart,
                                               lpart, cnt, wvT, d_in[6],
                                               d_out, flag);
  } else if (ws_size >= need2) {
    float* lpart = (float*)(ws + 16777216 + 2UL * NP * 64 * 4);
    attn_split<<<512, 256, 0, stream>>>(xc, y, qb, kb, xT, Opart, lpart, 1);
    combine_kernel<<<1024, 128, 0, stream>>>(Opart, lpart, wvT, d_in[6], d_out,
                                             flag, 2);
  } else {
    attn_kernel<<<512, 256, 0, stream>>>(xc, y, qb, kb, xT, wvT, d_in[6],
                                         d_out, flag);
  }
}

// Round 8
// 191.172 us; speedup vs baseline: 1.4005x; 1.4005x over previous
//
#include <hip/hip_runtime.h>
#include <hip/hip_bf16.h>
#include <math.h>

// B=8, S=4096, D_IN=64, H=512 single-head attention, fp32 I/O (dtype-probed).
// scores = x (Wq Wk^T) x^T / sqrt(H); out = softmax(scores) x Wv + bv.
// Folded biases: qb[s]=x_s·(Wq bk)+bq·bk, kb[t]=x_t·(Wk bq); +bv passes thru.
// R15 = revert R14's fused combine (agent-scope acquire fences invalidate L2
// device-wide -> FETCH 6.3->23.3MB, MfmaUtil 22->8.4, 175us; the kernel
// boundary is the cheap fence). Back to R12 (attn 65us) plus:
//  (a) combine blocks XCD-aligned with their writer batch (batch=blk&7, same
//      mapping attn uses) so the 33.6MB partial reads hit the writer XCD's
//      L2 at stream boundary;
//  (b) dtype_probe dispatch deleted - prep computes the flag per-block
//      locally and block 64 publishes it for proj/attn/combine.

#define SS 4096
#define DD 64
#define HH 512

#define CSCALE ((float)(1.4426950408889634 * 0.04419417382415922))

typedef __bf16 bf16x8 __attribute__((ext_vector_type(8)));
typedef float  f32x4  __attribute__((ext_vector_type(4)));
typedef float  f32x16 __attribute__((ext_vector_type(16)));
typedef unsigned int u32x4 __attribute__((ext_vector_type(4)));

__device__ __forceinline__ float b2f(__hip_bfloat16 v) { return __bfloat162float(v); }

__device__ __forceinline__ f32x4 mfma16(bf16x8 a, bf16x8 b, f32x4 c) {
  return __builtin_amdgcn_mfma_f32_16x16x32_bf16(a, b, c, 0, 0, 0);
}
__device__ __forceinline__ f32x16 mfma32(bf16x8 a, bf16x8 b, f32x16 c) {
  return __builtin_amdgcn_mfma_f32_32x32x16_bf16(a, b, c, 0, 0, 0);
}

__device__ __forceinline__ unsigned pack2(float a, float b) {
  float2 f2; f2.x = a; f2.y = b;
  __hip_bfloat162 h2 = __float22bfloat162_rn(f2);   // a in low 16
  unsigned u; __builtin_memcpy(&u, &h2, 4);
  return u;
}

__device__ __forceinline__ float loadf(const void* p, size_t i, int isF32) {
  return isF32 ? ((const float*)p)[i] : b2f(((const __hip_bfloat16*)p)[i]);
}
__device__ __forceinline__ void load8f(const void* p, size_t i, int isF32, float* o) {
  if (isF32) {
    const float4 a = *(const float4*)((const float*)p + i);
    const float4 b = *(const float4*)((const float*)p + i + 4);
    o[0]=a.x; o[1]=a.y; o[2]=a.z; o[3]=a.w; o[4]=b.x; o[5]=b.y; o[6]=b.z; o[7]=b.w;
  } else {
    const bf16x8 v = *(const bf16x8*)((const __hip_bfloat16*)p + i);
#pragma unroll
    for (int k = 0; k < 8; ++k) { __hip_bfloat16 h; __builtin_memcpy(&h, ((const unsigned short*)&v) + k, 2); o[k] = b2f(h); }
  }
}

// per-wave dtype probe (lane 0..63), returns 1 if Wq looks fp32
__device__ __forceinline__ int probe_f32(const void* Wq, int lane) {
  const unsigned short* h = (const unsigned short*)Wq;
  unsigned int bits = ((unsigned int)h[lane * 2]) << 16;
  float v; __builtin_memcpy(&v, &bits, 4);
  v = fabsf(v);
  if (!isfinite(v) || v > 1e10f) v = 1e10f;
  for (int off = 1; off < 64; off <<= 1) v = fmaxf(v, __shfl_xor(v, off, 64));
  return (v > 1e6f) ? 1 : 0;
}

// ---------------- prep: MT=(Wq Wk^T)^T bf16, u, w, c, wvT, flag ------------
__global__ __launch_bounds__(256) void prep_kernel(
    const void* __restrict__ Wq, const void* __restrict__ Wk,
    const void* __restrict__ Wv, const void* __restrict__ bq,
    const void* __restrict__ bk, __hip_bfloat16* __restrict__ MT,
    float* __restrict__ u, float* __restrict__ w_, float* __restrict__ c_,
    __hip_bfloat16* __restrict__ wvT, int* __restrict__ flag) {
  const int t = threadIdx.x, blk = blockIdx.x;
  __shared__ int fS;
  if (t < 64) { const int f = probe_f32(Wq, t); if (t == 0) fS = f; }
  __syncthreads();
  const int isF32 = fS;
  if (blk < 64) {
    __shared__ float red[256];
    const int i = blk, j = t >> 2, part = t & 3;
    float acc = 0.f, aq[8], ak[8];
    for (int c = 0; c < 16; ++c) {
      load8f(Wq, (size_t)i * HH + part * 128 + c * 8, isF32, aq);
      load8f(Wk, (size_t)j * HH + part * 128 + c * 8, isF32, ak);
#pragma unroll
      for (int k = 0; k < 8; ++k) acc = fmaf(aq[k], ak[k], acc);
    }
    red[t] = acc;
    __syncthreads();
    if (t < 64)
      MT[t * 64 + i] = __float2bfloat16(red[t*4] + red[t*4+1] + red[t*4+2] + red[t*4+3]);
  } else if (blk == 64) {
    __shared__ float pu[256], pw[256], pc[64];
    const int i = t & 63, part = t >> 6;
    float au = 0.f, aw = 0.f, v1[8], v2[8];
    for (int c = 0; c < 16; ++c) {
      load8f(Wq, (size_t)i * HH + part * 128 + c * 8, isF32, v1);
      load8f(bk, part * 128 + c * 8, isF32, v2);
#pragma unroll
      for (int k = 0; k < 8; ++k) au = fmaf(v1[k], v2[k], au);
      load8f(Wk, (size_t)i * HH + part * 128 + c * 8, isF32, v1);
      load8f(bq, part * 128 + c * 8, isF32, v2);
#pragma unroll
      for (int k = 0; k < 8; ++k) aw = fmaf(v1[k], v2[k], aw);
    }
    pu[t] = au; pw[t] = aw;
    if (t < 64) {
      float s = 0.f;
      for (int e = 0; e < 8; ++e)
        s = fmaf(loadf(bq, t * 8 + e, isF32), loadf(bk, t * 8 + e, isF32), s);
      pc[t] = s;
    }
    __syncthreads();
    if (t < 64) {
      u[t]  = pu[t] + pu[t+64] + pu[t+128] + pu[t+192];
      w_[t] = pw[t] + pw[t+64] + pw[t+128] + pw[t+192];
    }
    if (t == 0) {
      float s = 0.f;
      for (int e = 0; e < 64; ++e) s += pc[e];
      *c_ = s;
      *flag = isF32;                      // publish for proj/attn/combine
    }
  } else {
    const int base = (blk - 65) * 2048 + t;
    for (int r = 0; r < 8; ++r) {
      const int e = base + r * 256;          // e = h*64 + d
      const int h = e >> 6, d = e & 63;
      wvT[e] = __float2bfloat16(loadf(Wv, (size_t)d * HH + h, isF32));
    }
  }
}

// ---------------- proj: xc, y = x*M (MFMA), qb/kb, xT ----------------------
__global__ __launch_bounds__(256) void proj_kernel(
    const void* __restrict__ xraw, const __hip_bfloat16* __restrict__ MT,
    const float* __restrict__ u, const float* __restrict__ w_,
    const float* __restrict__ c_, __hip_bfloat16* __restrict__ xc,
    __hip_bfloat16* __restrict__ y, float* __restrict__ qb,
    float* __restrict__ kb, __hip_bfloat16* __restrict__ xT,
    const int* __restrict__ flag) {
  __shared__ __hip_bfloat16 xs[64 * 72];
  __shared__ __hip_bfloat16 Ms[64 * 72];   // MT staged: Ms[ycol][d]
  __shared__ float us[64], wl[64];
  __shared__ float cs;

  const int t = threadIdx.x;
  const int isF32 = *flag;
  {
    const int r = t >> 2, cb = (t & 3) * 16;
    *(bf16x8*)(&Ms[r * 72 + cb])     = *(const bf16x8*)(MT + r * 64 + cb);
    *(bf16x8*)(&Ms[r * 72 + cb + 8]) = *(const bf16x8*)(MT + r * 64 + cb + 8);
  }
  if (t < 64) { us[t] = u[t]; wl[t] = w_[t]; }
  if (t == 0) cs = *c_;

  const int b = blockIdx.x & 7;
  const int sbase = (blockIdx.x >> 3) * 64;
  const int rbase = b * SS + sbase;

  for (int i = 0; i < 2; ++i) {
    const int e = i * 256 + t;
    const int row = e >> 3, col = (e & 7) * 8;
    float v[8];
    load8f(xraw, (size_t)(rbase + row) * DD + col, isF32, v);
    __hip_bfloat16* dp = xs + row * 72 + col;
#pragma unroll
    for (int k = 0; k < 8; ++k) dp[k] = __float2bfloat16(v[k]);
  }
  __syncthreads();

  const int wv = t >> 6, lane = t & 63;
  const int l16 = lane & 15, quad = lane >> 4;
  // y tile: wave = 16 rows; A[m=row][k=d]
  const bf16x8 A0 = *(const bf16x8*)(&xs[(wv * 16 + l16) * 72 + quad * 8]);
  const bf16x8 A1 = *(const bf16x8*)(&xs[(wv * 16 + l16) * 72 + 32 + quad * 8]);
#pragma unroll
  for (int nt = 0; nt < 4; ++nt) {
    const bf16x8 B0 = *(const bf16x8*)(&Ms[(nt * 16 + l16) * 72 + quad * 8]);
    const bf16x8 B1 = *(const bf16x8*)(&Ms[(nt * 16 + l16) * 72 + 32 + quad * 8]);
    f32x4 C = (f32x4){0.f, 0.f, 0.f, 0.f};
    C = mfma16(A0, B0, C);
    C = mfma16(A1, B1, C);
#pragma unroll
    for (int r = 0; r < 4; ++r)
      y[(size_t)(rbase + wv * 16 + quad * 4 + r) * DD + nt * 16 + l16] =
          __float2bfloat16(C[r]);
  }
  if (t < 64) {
    float qa = 0.f, ka = 0.f;
    for (int d = 0; d < 64; ++d) {
      const float xv = b2f(xs[t * 72 + d]);
      qa = fmaf(xv, us[d], qa);
      ka = fmaf(xv, wl[d], ka);
    }
    qb[rbase + t] = (qa + cs) * CSCALE;
    kb[rbase + t] = ka * CSCALE;
  }
  for (int i = 0; i < 2; ++i) {
    const int e = i * 256 + t;
    const int row = e >> 3, col = (e & 7) * 8;
    *(bf16x8*)(xc + (size_t)(rbase + row) * DD + col) = *(const bf16x8*)(xs + row * 72 + col);
  }
  for (int i = 0; i < 16; ++i) {
    const int d = i * 4 + (t >> 6);
    const int sl = t & 63;
    xT[((size_t)b * DD + d) * SS + sbase + sl] = xs[sl * 72 + d];
  }
}

// ---------------- attn_split: 32x32 MFMA flash over a key slice ------------
// grid 8*nspl*32: b=blk&7 (XCD), ks=(blk>>3)&(nspl-1), qg=blk>>(3+lgs).
// Block = 128 queries (4 waves x 32). Writes unnormalized O + row-sums l.
__global__ __launch_bounds__(256) void attn_split(
    const __hip_bfloat16* __restrict__ x,
    const __hip_bfloat16* __restrict__ y,
    const float* __restrict__ qb, const float* __restrict__ kb,
    const __hip_bfloat16* __restrict__ xT,
    float* __restrict__ Opart, float* __restrict__ lpart, int lgs) {
  __shared__ __hip_bfloat16 xs[2][32 * 72];    // 9.2 KB (X tile, tau-permuted)
  __shared__ __hip_bfloat16 vsm[2][64 * 40];   // 10.2 KB (V tile [d][key])
  const int tid = threadIdx.x;
  const int wv = tid >> 6, lane = tid & 63;
  const int l32 = lane & 31, hi = lane >> 5;
  const int b = blockIdx.x & 7;
  const int nspl = 1 << lgs;
  const int ks = (blockIdx.x >> 3) & (nspl - 1);
  const int qg = blockIdx.x >> (3 + lgs);
  const int kspl = SS >> lgs;
  const int koff = ks * kspl;
  const size_t rowq = ((size_t)b << 12) + (size_t)qg * 128 + wv * 32;

  // Y frags (B-operand of S^T): lane needs Y[q=l32][d=16mi+8hi+j]
  bf16x8 Y[4];
#pragma unroll
  for (int mi = 0; mi < 4; ++mi)
    Y[mi] = *(const bf16x8*)(y + (rowq + l32) * DD + mi * 16 + hi * 8);
  const float qbl = qb[rowq + l32];

  // staging: key sxr -> LDS row tau(sxr); V: [d][key] rows of 40
  const int sxr = tid >> 3, sxc = (tid & 7) * 8;
  const int g = sxr >> 2;
  const int taur = (sxr & 3) + 4 * ((g & 4) | ((g & 1) << 1) | ((g >> 1) & 1));
  const int svd = tid >> 2, svc = (tid & 3) * 8;
  const __hip_bfloat16* gx = x + ((size_t)b * SS + koff + sxr) * DD + sxc;
  const __hip_bfloat16* gv = xT + ((size_t)b * DD + svd) * SS + koff + svc;
  const float* kbp = kb + (size_t)b * SS + koff + hi * 8;

  // prologue: tile 0 -> buf 0; tile 1 -> regs
  bf16x8 nx = *(const bf16x8*)gx;
  bf16x8 nv = *(const bf16x8*)gv;
  *(bf16x8*)(&xs[0][taur * 72 + sxc]) = nx;
  *(bf16x8*)(&vsm[0][svd * 40 + svc]) = nv;
  nx = *(const bf16x8*)(gx + 32 * DD);
  nv = *(const bf16x8*)(gv + 32);
  __syncthreads();

  f32x16 O0, O1;
#pragma unroll
  for (int r = 0; r < 16; ++r) { O0[r] = 0.f; O1[r] = 0.f; }
  float lp = 0.f;

  for (int kt = 0; kt < kspl; kt += 32) {
    const int p = (kt >> 5) & 1, np = p ^ 1;
    if (kt + 32 < kspl) {
      *(bf16x8*)(&xs[np][taur * 72 + sxc]) = nx;
      *(bf16x8*)(&vsm[np][svd * 40 + svc]) = nv;
      if (kt + 64 < kspl) {
        nx = *(const bf16x8*)(gx + (size_t)(kt + 64) * DD);
        nv = *(const bf16x8*)(gv + (kt + 64));
      }
    }
    // kb for this tile (L2): reg r <-> key 8hi+(r&7)+16(r>>3)
    const f32x4 kb0a = *(const f32x4*)(kbp + kt);
    const f32x4 kb0b = *(const f32x4*)(kbp + kt + 4);
    const f32x4 kb1a = *(const f32x4*)(kbp + kt + 16);
    const f32x4 kb1b = *(const f32x4*)(kbp + kt + 20);

    // X A-frags: row l32 (tau-permuted keys), cols 16mi+8hi+j
    const bf16x8 A0 = *(const bf16x8*)(&xs[p][l32 * 72 + hi * 8]);
    const bf16x8 A1 = *(const bf16x8*)(&xs[p][l32 * 72 + 16 + hi * 8]);
    const bf16x8 A2 = *(const bf16x8*)(&xs[p][l32 * 72 + 32 + hi * 8]);
    const bf16x8 A3 = *(const bf16x8*)(&xs[p][l32 * 72 + 48 + hi * 8]);

    f32x16 S;
#pragma unroll
    for (int r = 0; r < 16; ++r) S[r] = 0.f;
    S = mfma32(A0, Y[0], S);
    S = mfma32(A1, Y[1], S);
    S = mfma32(A2, Y[2], S);
    S = mfma32(A3, Y[3], S);

    float pv[16];
#pragma unroll
    for (int r = 0; r < 16; ++r) {
      const float kv = (r < 4) ? kb0a[r & 3]
                     : (r < 8) ? kb0b[r & 3]
                     : (r < 12) ? kb1a[r & 3] : kb1b[r & 3];
      pv[r] = __builtin_amdgcn_exp2f(fmaf(S[r], CSCALE, qbl + kv));
    }
    // row-sum partial (this lane's 16 keys of its query)
    {
      float s0 = (pv[0]+pv[1]) + (pv[2]+pv[3]);
      float s1 = (pv[4]+pv[5]) + (pv[6]+pv[7]);
      float s2 = (pv[8]+pv[9]) + (pv[10]+pv[11]);
      float s3 = (pv[12]+pv[13]) + (pv[14]+pv[15]);
      lp += (s0 + s1) + (s2 + s3);
    }
    // PV A-frags: C-reg order IS operand order (tau construction)
    u32x4 R0, R1;
    R0[0] = pack2(pv[0], pv[1]);  R0[1] = pack2(pv[2], pv[3]);
    R0[2] = pack2(pv[4], pv[5]);  R0[3] = pack2(pv[6], pv[7]);
    R1[0] = pack2(pv[8], pv[9]);  R1[1] = pack2(pv[10], pv[11]);
    R1[2] = pack2(pv[12], pv[13]); R1[3] = pack2(pv[14], pv[15]);
    bf16x8 Pf0, Pf1;
    __builtin_memcpy(&Pf0, &R0, 16);
    __builtin_memcpy(&Pf1, &R1, 16);

    // V B-frags: col d = l32+32md, rows keys 16mk+8hi+j
    const bf16x8 V00 = *(const bf16x8*)(&vsm[p][l32 * 40 + hi * 8]);
    const bf16x8 V10 = *(const bf16x8*)(&vsm[p][l32 * 40 + 16 + hi * 8]);
    const bf16x8 V01 = *(const bf16x8*)(&vsm[p][(l32 + 32) * 40 + hi * 8]);
    const bf16x8 V11 = *(const bf16x8*)(&vsm[p][(l32 + 32) * 40 + 16 + hi * 8]);

    O0 = mfma32(Pf0, V00, O0);
    O0 = mfma32(Pf1, V10, O0);
    O1 = mfma32(Pf0, V01, O1);
    O1 = mfma32(Pf1, V11, O1);

    __syncthreads();
  }

  // merge l across hi halves (lane l and l^32 hold same query)
  lp += __shfl_xor(lp, 32, 64);
  const size_t NP = (size_t)SS * 8;
  if (hi == 0) lpart[(size_t)ks * NP + rowq + l32] = lp;

  // O write: lane = d-col (l32 + 32md), reg = query (r&3)+8*(r>>2)+4hi
  float* Op = Opart + ((size_t)ks * NP + rowq) * 64;
#pragma unroll
  for (int r = 0; r < 16; ++r) {
    const int qrow = (r & 3) + 8 * (r >> 2) + 4 * hi;
    Op[(size_t)qrow * 64 + l32]      = O0[r];
    Op[(size_t)qrow * 64 + 32 + l32] = O1[r];
  }
}

// ---------------- combine: merge splits, normalize, out-projection ---------
// XCD-aligned: batch = blk&7 matches the writer blocks' XCD so partial reads
// hit that XCD's L2 (no fences needed across the kernel boundary).
__global__ __launch_bounds__(128) void combine_kernel(
    const float* __restrict__ Opart, const float* __restrict__ lpart,
    const __hip_bfloat16* __restrict__ wvT, const void* __restrict__ bv_raw,
    void* __restrict__ out_raw, const int* __restrict__ flag, int nspl) {
  const int tid = threadIdx.x;
  const int wv = tid >> 6, lane = tid & 63;
  const int l16 = lane & 15, quad = lane >> 4;
  const int bb = blockIdx.x & 7;                 // batch -> writer XCD
  const int gg = blockIdx.x >> 3;                // 0..127 within batch
  const size_t q0 = ((size_t)bb << 12) + (size_t)gg * 32 + (size_t)wv * 16;
  const int isF32 = *flag;
  const size_t NP = (size_t)SS * 8;   // 32768 queries per split

  float lsum = 0.f;
  for (int s = 0; s < nspl; ++s) lsum += lpart[(size_t)s * NP + q0 + l16];
  const float linv = (lsum > 0.f) ? 1.0f / lsum : 0.f;

  float vlo[8], vhi[8];
#pragma unroll
  for (int j = 0; j < 8; ++j) { vlo[j] = 0.f; vhi[j] = 0.f; }
  for (int s = 0; s < nspl; ++s) {
    const float* p0 = Opart + ((size_t)s * NP + q0 + l16) * 64 + quad * 8;
#pragma unroll
    for (int j = 0; j < 8; j += 4) {
      const float4 a = *(const float4*)(p0 + j);
      vlo[j]   += a.x; vlo[j+1] += a.y; vlo[j+2] += a.z; vlo[j+3] += a.w;
      const float4 c = *(const float4*)(p0 + 32 + j);
      vhi[j]   += c.x; vhi[j+1] += c.y; vhi[j+2] += c.z; vhi[j+3] += c.w;
    }
  }
  u32x4 Rlo, Rhi;
#pragma unroll
  for (int j = 0; j < 4; ++j) {
    Rlo[j] = pack2(vlo[2*j] * linv, vlo[2*j+1] * linv);
    Rhi[j] = pack2(vhi[2*j] * linv, vhi[2*j+1] * linv);
  }
  bf16x8 Alo, Ahi;
  __builtin_memcpy(&Alo, &Rlo, 16);
  __builtin_memcpy(&Ahi, &Rhi, 16);

  float* outf = (float*)out_raw;
  __hip_bfloat16* outb = (__hip_bfloat16*)out_raw;
#pragma unroll 4
  for (int ht = 0; ht < 32; ++ht) {
    const __hip_bfloat16* wp = wvT + (size_t)(ht * 16 + l16) * DD + quad * 8;
    const bf16x8 Wlo = *(const bf16x8*)wp;
    const bf16x8 Whi = *(const bf16x8*)(wp + 32);
    f32x4 C = (f32x4){0.f, 0.f, 0.f, 0.f};
    C = mfma16(Alo, Wlo, C);
    C = mfma16(Ahi, Whi, C);
    const float bvv = loadf(bv_raw, ht * 16 + l16, isF32);
#pragma unroll
    for (int r = 0; r < 4; ++r) {
      const size_t oidx = (q0 + quad * 4 + r) * HH + ht * 16 + l16;
      const float val = C[r] + bvv;
      if (isF32) outf[oidx] = val;
      else       outb[oidx] = __float2bfloat16(val);
    }
  }
}

// ---------------- attn: R10 fallback (single pass, used if ws too small) ---
__global__ __launch_bounds__(256) void attn_kernel(
    const __hip_bfloat16* __restrict__ x,
    const __hip_bfloat16* __restrict__ y,
    const float* __restrict__ qb, const float* __restrict__ kb,
    const __hip_bfloat16* __restrict__ xT,
    const __hip_bfloat16* __restrict__ wvT,
    const void* __restrict__ bv_raw,
    void* __restrict__ out_raw, const int* __restrict__ flag) {
  __shared__ __hip_bfloat16 xs[2][32 * 72];
  __shared__ __hip_bfloat16 vsm[2][64 * 40];
  __shared__ float kbl[SS];
  const int tid = threadIdx.x;
  const int wv = tid >> 6, lane = tid & 63;
  const int l16 = lane & 15, quad = lane >> 4;
  const int b = blockIdx.x & 7;
  const int qt = (blockIdx.x >> 3) * 4 + wv;
  const size_t rowq = ((size_t)b << 12) + ((size_t)qt << 4);
  const int isF32 = *flag;

  const __hip_bfloat16* xb  = x  + ((size_t)b * SS) * DD;
  const __hip_bfloat16* xTb = xT + ((size_t)b * DD) * SS;
  const float* kbb = kb + ((size_t)b * SS);

  const __hip_bfloat16* yp = y + (rowq + l16) * DD + quad * 8;
  const bf16x8 Ylo = *(const bf16x8*)yp;
  const bf16x8 Yhi = *(const bf16x8*)(yp + 32);
  const float qbl = qb[rowq + l16];

  const int sxr = tid >> 3, sxc = (tid & 7) * 8;
  const int taur = (sxr & 3) + ((sxr >> 3) << 2) + (((sxr >> 2) & 1) << 4);
  const int svd = tid >> 2, svc = (tid & 3) * 8;
  const __hip_bfloat16* gx = xb + (size_t)sxr * DD + sxc;
  const __hip_bfloat16* gv = xTb + (size_t)svd * SS + svc;

#pragma unroll
  for (int j = 0; j < 4; ++j) {
    const int c = j * 256 + tid;
    *(f32x4*)(&kbl[c * 4]) = *(const f32x4*)(kbb + c * 4);
  }

  bf16x8 nx = *(const bf16x8*)gx;
  bf16x8 nv = *(const bf16x8*)gv;
  *(bf16x8*)(&xs[0][taur * 72 + sxc]) = nx;
  *(bf16x8*)(&vsm[0][svd * 40 + svc]) = nv;
  nx = *(const bf16x8*)(gx + 32 * DD);
  nv = *(const bf16x8*)(gv + 32);
  __syncthreads();

  bf16x8 onesb;
#pragma unroll
  for (int j = 0; j < 8; ++j) onesb[j] = (__bf16)1.0f;

  f32x4 O[4];
#pragma unroll
  for (int n = 0; n < 4; ++n) O[n] = (f32x4){0.f, 0.f, 0.f, 0.f};
  f32x4 Ol = (f32x4){0.f, 0.f, 0.f, 0.f};

  for (int kt = 0; kt < SS; kt += 32) {
    const int p = (kt >> 5) & 1, np = p ^ 1;
    if (kt + 32 < SS) {
      *(bf16x8*)(&xs[np][taur * 72 + sxc]) = nx;
      *(bf16x8*)(&vsm[np][svd * 40 + svc]) = nv;
      if (kt + 64 < SS) {
        nx = *(const bf16x8*)(gx + (size_t)(kt + 64) * DD);
        nv = *(const bf16x8*)(gv + (kt + 64));
      }
    }
    const bf16x8 B00 = *(const bf16x8*)(&xs[p][l16 * 72 + quad * 8]);
    const bf16x8 B01 = *(const bf16x8*)(&xs[p][l16 * 72 + 32 + quad * 8]);
    const bf16x8 B10 = *(const bf16x8*)(&xs[p][(16 + l16) * 72 + quad * 8]);
    const bf16x8 B11 = *(const bf16x8*)(&xs[p][(16 + l16) * 72 + 32 + quad * 8]);
    const bf16x8 V0 = *(const bf16x8*)(&vsm[p][l16 * 40 + quad * 8]);
    const bf16x8 V1 = *(const bf16x8*)(&vsm[p][(16 + l16) * 40 + quad * 8]);
    const bf16x8 V2 = *(const bf16x8*)(&vsm[p][(32 + l16) * 40 + quad * 8]);
    const bf16x8 V3 = *(const bf16x8*)(&vsm[p][(48 + l16) * 40 + quad * 8]);

    f32x4 S0 = (f32x4){0.f, 0.f, 0.f, 0.f};
    f32x4 S1 = (f32x4){0.f, 0.f, 0.f, 0.f};
    S0 = mfma16(B00, Ylo, S0);
    S0 = mfma16(B01, Yhi, S0);
    S1 = mfma16(B10, Ylo, S1);
    S1 = mfma16(B11, Yhi, S1);

    const f32x4 kb0 = *(const f32x4*)(&kbl[kt + quad * 8]);
    const f32x4 kb1 = *(const f32x4*)(&kbl[kt + quad * 8 + 4]);

    float p0[4], p1[4];
#pragma unroll
    for (int r = 0; r < 4; ++r) {
      p0[r] = __builtin_amdgcn_exp2f(fmaf(S0[r], CSCALE, qbl + kb0[r]));
      p1[r] = __builtin_amdgcn_exp2f(fmaf(S1[r], CSCALE, qbl + kb1[r]));
    }
    u32x4 R;
    R[0] = pack2(p0[0], p0[1]);
    R[1] = pack2(p0[2], p0[3]);
    R[2] = pack2(p1[0], p1[1]);
    R[3] = pack2(p1[2], p1[3]);
    bf16x8 Pf;
    __builtin_memcpy(&Pf, &R, 16);

    O[0] = mfma16(Pf, V0, O[0]);
    O[1] = mfma16(Pf, V1, O[1]);
    O[2] = mfma16(Pf, V2, O[2]);
    O[3] = mfma16(Pf, V3, O[3]);
    Ol = mfma16(Pf, onesb, Ol);

    __syncthreads();
  }

  float inv_l[4];
#pragma unroll
  for (int r = 0; r < 4; ++r)
    inv_l[r] = (Ol[r] > 0.f) ? 1.0f / Ol[r] : 0.f;
  __hip_bfloat16* pl = &xs[0][0] + wv * 1152;
#pragma unroll
  for (int n = 0; n < 4; ++n)
#pragma unroll
    for (int r = 0; r < 4; ++r) {
      const int row = quad * 4 + r;
      pl[row * 72 + n * 16 + l16] = __float2bfloat16(O[n][r] * inv_l[r]);
    }
  __syncthreads();
  const bf16x8 Alo = *(const bf16x8*)(pl + l16 * 72 + quad * 8);
  const bf16x8 Ahi = *(const bf16x8*)(pl + l16 * 72 + 32 + quad * 8);

  float* outf = (float*)out_raw;
  __hip_bfloat16* outb = (__hip_bfloat16*)out_raw;
#pragma unroll 4
  for (int ht = 0; ht < 32; ++ht) {
    const __hip_bfloat16* wp = wvT + (size_t)(ht * 16 + l16) * DD + quad * 8;
    const bf16x8 Wlo = *(const bf16x8*)wp;
    const bf16x8 Whi = *(const bf16x8*)(wp + 32);
    f32x4 C = (f32x4){0.f, 0.f, 0.f, 0.f};
    C = mfma16(Alo, Wlo, C);
    C = mfma16(Ahi, Whi, C);
    const float bvv = loadf(bv_raw, ht * 16 + l16, isF32);
#pragma unroll
    for (int r = 0; r < 4; ++r) {
      const size_t oidx = (rowq + quad * 4 + r) * HH + ht * 16 + l16;
      const float val = C[r] + bvv;
      if (isF32) outf[oidx] = val;
      else       outb[oidx] = __float2bfloat16(val);
    }
  }
}

// ---------------- launcher --------------------------------------------------
extern "C" void kernel_launch(void* const* d_in, const int* in_sizes, int n_in,
                              void* d_out, int out_size, void* d_ws,
                              size_t ws_size, hipStream_t stream) {
  char* ws = (char*)d_ws;
  int*   flag = (int*)(ws + 0);
  __hip_bfloat16* MT = (__hip_bfloat16*)(ws + 1024);       // 8 KB
  float* u    = (float*)(ws + 9216);
  float* w_   = (float*)(ws + 9728);
  float* c_   = (float*)(ws + 10240);
  __hip_bfloat16* wvT = (__hip_bfloat16*)(ws + 32768);     // 64 KB
  __hip_bfloat16* xc  = (__hip_bfloat16*)(ws + 131072);    // 4 MB
  __hip_bfloat16* y   = (__hip_bfloat16*)(ws + 4325376);   // 4 MB
  float* qb = (float*)(ws + 8519680);                       // 128 KB
  float* kb = (float*)(ws + 8650752);                       // 128 KB
  __hip_bfloat16* xT = (__hip_bfloat16*)(ws + 8781824);    // 4 MB
  float* Opart = (float*)(ws + 16777216);                   // up to 32 MB
  const size_t NP = (size_t)SS * 8;
  const size_t need4 = 16777216UL + 4UL * NP * 64 * 4 + 4UL * NP * 4;  // ~50.9 MB
  const size_t need2 = 16777216UL + 2UL * NP * 64 * 4 + 2UL * NP * 4;  // ~33.8 MB

  prep_kernel<<<81, 256, 0, stream>>>(d_in[1], d_in[3], d_in[5], d_in[2],
                                      d_in[4], MT, u, w_, c_, wvT, flag);
  proj_kernel<<<512, 256, 0, stream>>>(d_in[0], MT, u, w_, c_, xc, y, qb, kb,
                                       xT, flag);
  if (ws_size >= need4) {
    float* lpart = (float*)(ws + 16777216 + 4UL * NP * 64 * 4);
    attn_split<<<1024, 256, 0, stream>>>(xc, y, qb, kb, xT, Opart, lpart, 2);
    combine_kernel<<<1024, 128, 0, stream>>>(Opart, lpart, wvT, d_in[6], d_out,
                                             flag, 4);
  } else if (ws_size >= need2) {
    float* lpart = (float*)(ws + 16777216 + 2UL * NP * 64 * 4);
    attn_split<<<512, 256, 0, stream>>>(xc, y, qb, kb, xT, Opart, lpart, 1);
    combine_kernel<<<1024, 128, 0, stream>>>(Opart, lpart, wvT, d_in[6], d_out,
                                             flag, 2);
  } else {
    attn_kernel<<<512, 256, 0, stream>>>(xc, y, qb, kb, xT, wvT, d_in[6],
                                         d_out, flag);
  }
}

// Round 9
// 190.607 us; speedup vs baseline: 1.4046x; 1.0030x over previous
//
#include <hip/hip_runtime.h>
#include <hip/hip_bf16.h>
#include <math.h>

// B=8, S=4096, D_IN=64, H=512 single-head attention, fp32 I/O (dtype-probed).
// scores = x (Wq Wk^T) x^T / sqrt(H); out = softmax(scores) x Wv + bv.
// Folded biases: qb[s]=x_s·(Wq bk)+bq·bk, kb[t]=x_t·(Wk bq); +bv passes thru.
// R16: attn_split is proven-stable at 65us; the hidden 86us is prep+proj+
// gaps (same in R10 and R15 ledgers). proj violated G13: y-write was 16
// scalar 2B stores/thread, xT-write 16 scalar stores + stride-72 LDS reads,
// qb/kb serial on 64/256 threads. Fix: stage y and xT through a 3rd LDS
// buffer, write bf16x8 (16B/lane); qb/kb 4 threads/row + shfl_xor reduce.
// combine: h-split x2 (grid 2048, 16 waves/CU) to fix latency-bound merge
// (was ~40us vs ~16us BW floor at 8 waves/CU); partial re-reads L2-hot.

#define SS 4096
#define DD 64
#define HH 512

#define CSCALE ((float)(1.4426950408889634 * 0.04419417382415922))

typedef __bf16 bf16x8 __attribute__((ext_vector_type(8)));
typedef float  f32x4  __attribute__((ext_vector_type(4)));
typedef float  f32x16 __attribute__((ext_vector_type(16)));
typedef unsigned int u32x4 __attribute__((ext_vector_type(4)));

__device__ __forceinline__ float b2f(__hip_bfloat16 v) { return __bfloat162float(v); }

__device__ __forceinline__ f32x4 mfma16(bf16x8 a, bf16x8 b, f32x4 c) {
  return __builtin_amdgcn_mfma_f32_16x16x32_bf16(a, b, c, 0, 0, 0);
}
__device__ __forceinline__ f32x16 mfma32(bf16x8 a, bf16x8 b, f32x16 c) {
  return __builtin_amdgcn_mfma_f32_32x32x16_bf16(a, b, c, 0, 0, 0);
}

__device__ __forceinline__ unsigned pack2(float a, float b) {
  float2 f2; f2.x = a; f2.y = b;
  __hip_bfloat162 h2 = __float22bfloat162_rn(f2);   // a in low 16
  unsigned u; __builtin_memcpy(&u, &h2, 4);
  return u;
}

__device__ __forceinline__ float loadf(const void* p, size_t i, int isF32) {
  return isF32 ? ((const float*)p)[i] : b2f(((const __hip_bfloat16*)p)[i]);
}
__device__ __forceinline__ void load8f(const void* p, size_t i, int isF32, float* o) {
  if (isF32) {
    const float4 a = *(const float4*)((const float*)p + i);
    const float4 b = *(const float4*)((const float*)p + i + 4);
    o[0]=a.x; o[1]=a.y; o[2]=a.z; o[3]=a.w; o[4]=b.x; o[5]=b.y; o[6]=b.z; o[7]=b.w;
  } else {
    const bf16x8 v = *(const bf16x8*)((const __hip_bfloat16*)p + i);
#pragma unroll
    for (int k = 0; k < 8; ++k) { __hip_bfloat16 h; __builtin_memcpy(&h, ((const unsigned short*)&v) + k, 2); o[k] = b2f(h); }
  }
}

// per-wave dtype probe (lane 0..63), returns 1 if Wq looks fp32
__device__ __forceinline__ int probe_f32(const void* Wq, int lane) {
  const unsigned short* h = (const unsigned short*)Wq;
  unsigned int bits = ((unsigned int)h[lane * 2]) << 16;
  float v; __builtin_memcpy(&v, &bits, 4);
  v = fabsf(v);
  if (!isfinite(v) || v > 1e10f) v = 1e10f;
  for (int off = 1; off < 64; off <<= 1) v = fmaxf(v, __shfl_xor(v, off, 64));
  return (v > 1e6f) ? 1 : 0;
}

// ---------------- prep: MT=(Wq Wk^T)^T bf16, u, w, c, wvT, flag ------------
__global__ __launch_bounds__(256) void prep_kernel(
    const void* __restrict__ Wq, const void* __restrict__ Wk,
    const void* __restrict__ Wv, const void* __restrict__ bq,
    const void* __restrict__ bk, __hip_bfloat16* __restrict__ MT,
    float* __restrict__ u, float* __restrict__ w_, float* __restrict__ c_,
    __hip_bfloat16* __restrict__ wvT, int* __restrict__ flag) {
  const int t = threadIdx.x, blk = blockIdx.x;
  __shared__ int fS;
  if (t < 64) { const int f = probe_f32(Wq, t); if (t == 0) fS = f; }
  __syncthreads();
  const int isF32 = fS;
  if (blk < 64) {
    __shared__ float red[256];
    const int i = blk, j = t >> 2, part = t & 3;
    float acc = 0.f, aq[8], ak[8];
    for (int c = 0; c < 16; ++c) {
      load8f(Wq, (size_t)i * HH + part * 128 + c * 8, isF32, aq);
      load8f(Wk, (size_t)j * HH + part * 128 + c * 8, isF32, ak);
#pragma unroll
      for (int k = 0; k < 8; ++k) acc = fmaf(aq[k], ak[k], acc);
    }
    red[t] = acc;
    __syncthreads();
    if (t < 64)
      MT[t * 64 + i] = __float2bfloat16(red[t*4] + red[t*4+1] + red[t*4+2] + red[t*4+3]);
  } else if (blk == 64) {
    __shared__ float pu[256], pw[256], pc[64];
    const int i = t & 63, part = t >> 6;
    float au = 0.f, aw = 0.f, v1[8], v2[8];
    for (int c = 0; c < 16; ++c) {
      load8f(Wq, (size_t)i * HH + part * 128 + c * 8, isF32, v1);
      load8f(bk, part * 128 + c * 8, isF32, v2);
#pragma unroll
      for (int k = 0; k < 8; ++k) au = fmaf(v1[k], v2[k], au);
      load8f(Wk, (size_t)i * HH + part * 128 + c * 8, isF32, v1);
      load8f(bq, part * 128 + c * 8, isF32, v2);
#pragma unroll
      for (int k = 0; k < 8; ++k) aw = fmaf(v1[k], v2[k], aw);
    }
    pu[t] = au; pw[t] = aw;
    if (t < 64) {
      float s = 0.f;
      for (int e = 0; e < 8; ++e)
        s = fmaf(loadf(bq, t * 8 + e, isF32), loadf(bk, t * 8 + e, isF32), s);
      pc[t] = s;
    }
    __syncthreads();
    if (t < 64) {
      u[t]  = pu[t] + pu[t+64] + pu[t+128] + pu[t+192];
      w_[t] = pw[t] + pw[t+64] + pw[t+128] + pw[t+192];
    }
    if (t == 0) {
      float s = 0.f;
      for (int e = 0; e < 64; ++e) s += pc[e];
      *c_ = s;
      *flag = isF32;                      // publish for proj/attn/combine
    }
  } else {
    const int base = (blk - 65) * 2048 + t;
    for (int r = 0; r < 8; ++r) {
      const int e = base + r * 256;          // e = h*64 + d
      const int h = e >> 6, d = e & 63;
      wvT[e] = __float2bfloat16(loadf(Wv, (size_t)d * HH + h, isF32));
    }
  }
}

// ---------------- proj: xc, y = x*M (MFMA), qb/kb, xT (vectorized) ---------
__global__ __launch_bounds__(256) void proj_kernel(
    const void* __restrict__ xraw, const __hip_bfloat16* __restrict__ MT,
    const float* __restrict__ u, const float* __restrict__ w_,
    const float* __restrict__ c_, __hip_bfloat16* __restrict__ xc,
    __hip_bfloat16* __restrict__ y, float* __restrict__ qb,
    float* __restrict__ kb, __hip_bfloat16* __restrict__ xT,
    const int* __restrict__ flag) {
  __shared__ __hip_bfloat16 xs[64 * 72];
  __shared__ __hip_bfloat16 Ms[64 * 72];   // MT staged: Ms[ycol][d]
  __shared__ __hip_bfloat16 st[64 * 72];   // staging: y rows, then xT rows
  __shared__ float us[64], wl[64];
  __shared__ float cs;

  const int t = threadIdx.x;
  const int isF32 = *flag;
  {
    const int r = t >> 2, cb = (t & 3) * 16;
    *(bf16x8*)(&Ms[r * 72 + cb])     = *(const bf16x8*)(MT + r * 64 + cb);
    *(bf16x8*)(&Ms[r * 72 + cb + 8]) = *(const bf16x8*)(MT + r * 64 + cb + 8);
  }
  if (t < 64) { us[t] = u[t]; wl[t] = w_[t]; }
  if (t == 0) cs = *c_;

  const int b = blockIdx.x & 7;
  const int sbase = (blockIdx.x >> 3) * 64;
  const int rbase = b * SS + sbase;

  for (int i = 0; i < 2; ++i) {
    const int e = i * 256 + t;
    const int row = e >> 3, col = (e & 7) * 8;
    float v[8];
    load8f(xraw, (size_t)(rbase + row) * DD + col, isF32, v);
    __hip_bfloat16* dp = xs + row * 72 + col;
#pragma unroll
    for (int k = 0; k < 8; ++k) dp[k] = __float2bfloat16(v[k]);
  }
  __syncthreads();

  const int wv = t >> 6, lane = t & 63;
  const int l16 = lane & 15, quad = lane >> 4;
  // y tile: wave = 16 rows; A[m=row][k=d]
  const bf16x8 A0 = *(const bf16x8*)(&xs[(wv * 16 + l16) * 72 + quad * 8]);
  const bf16x8 A1 = *(const bf16x8*)(&xs[(wv * 16 + l16) * 72 + 32 + quad * 8]);
  float yC[4][4];
#pragma unroll
  for (int nt = 0; nt < 4; ++nt) {
    const bf16x8 B0 = *(const bf16x8*)(&Ms[(nt * 16 + l16) * 72 + quad * 8]);
    const bf16x8 B1 = *(const bf16x8*)(&Ms[(nt * 16 + l16) * 72 + 32 + quad * 8]);
    f32x4 C = (f32x4){0.f, 0.f, 0.f, 0.f};
    C = mfma16(A0, B0, C);
    C = mfma16(A1, B1, C);
#pragma unroll
    for (int r = 0; r < 4; ++r) yC[nt][r] = C[r];
  }

  // qb/kb: 4 threads per q-row (t>>2 = q, t&3 = d-quarter), shfl reduce
  {
    const int q = t >> 2, pp = (t & 3) * 16;
    float qa = 0.f, ka = 0.f;
#pragma unroll
    for (int dd = 0; dd < 16; ++dd) {
      const int d = pp + dd;
      const float xv = b2f(xs[q * 72 + d]);
      qa = fmaf(xv, us[d], qa);
      ka = fmaf(xv, wl[d], ka);
    }
    qa += __shfl_xor(qa, 1, 64); qa += __shfl_xor(qa, 2, 64);
    ka += __shfl_xor(ka, 1, 64); ka += __shfl_xor(ka, 2, 64);
    if ((t & 3) == 0) {
      qb[rbase + q] = (qa + cs) * CSCALE;
      kb[rbase + q] = ka * CSCALE;
    }
  }

  // xc write (vec, from xs)
  for (int i = 0; i < 2; ++i) {
    const int e = i * 256 + t;
    const int row = e >> 3, col = (e & 7) * 8;
    *(bf16x8*)(xc + (size_t)(rbase + row) * DD + col) = *(const bf16x8*)(xs + row * 72 + col);
  }

  // stage y in st (scalar LDS), then vectorized global write
#pragma unroll
  for (int nt = 0; nt < 4; ++nt)
#pragma unroll
    for (int r = 0; r < 4; ++r)
      st[(wv * 16 + quad * 4 + r) * 72 + nt * 16 + l16] = __float2bfloat16(yC[nt][r]);
  __syncthreads();
  {
    const int r = t >> 2, cb = (t & 3) * 16;
    *(bf16x8*)(y + (size_t)(rbase + r) * DD + cb)     = *(const bf16x8*)(&st[r * 72 + cb]);
    *(bf16x8*)(y + (size_t)(rbase + r) * DD + cb + 8) = *(const bf16x8*)(&st[r * 72 + cb + 8]);
  }
  __syncthreads();   // all reads of st done before transpose reuse

  // stage xT rows in st: st[d*72 + s] = xs[s*72 + d], then vec write
  {
    const int d = t >> 2, sc = (t & 3) * 16;
#pragma unroll
    for (int k = 0; k < 16; ++k)
      st[d * 72 + sc + k] = xs[(sc + k) * 72 + d];
  }
  __syncthreads();
  {
    const int d = t >> 2, sc = (t & 3) * 16;
    __hip_bfloat16* xp = xT + ((size_t)b * DD + d) * SS + sbase + sc;
    *(bf16x8*)(xp)     = *(const bf16x8*)(&st[d * 72 + sc]);
    *(bf16x8*)(xp + 8) = *(const bf16x8*)(&st[d * 72 + sc + 8]);
  }
}

// ---------------- attn_split: 32x32 MFMA flash over a key slice ------------
// grid 8*nspl*32: b=blk&7 (XCD), ks=(blk>>3)&(nspl-1), qg=blk>>(3+lgs).
// Block = 128 queries (4 waves x 32). Writes unnormalized O + row-sums l.
__global__ __launch_bounds__(256) void attn_split(
    const __hip_bfloat16* __restrict__ x,
    const __hip_bfloat16* __restrict__ y,
    const float* __restrict__ qb, const float* __restrict__ kb,
    const __hip_bfloat16* __restrict__ xT,
    float* __restrict__ Opart, float* __restrict__ lpart, int lgs) {
  __shared__ __hip_bfloat16 xs[2][32 * 72];    // 9.2 KB (X tile, tau-permuted)
  __shared__ __hip_bfloat16 vsm[2][64 * 40];   // 10.2 KB (V tile [d][key])
  const int tid = threadIdx.x;
  const int wv = tid >> 6, lane = tid & 63;
  const int l32 = lane & 31, hi = lane >> 5;
  const int b = blockIdx.x & 7;
  const int nspl = 1 << lgs;
  const int ks = (blockIdx.x >> 3) & (nspl - 1);
  const int qg = blockIdx.x >> (3 + lgs);
  const int kspl = SS >> lgs;
  const int koff = ks * kspl;
  const size_t rowq = ((size_t)b << 12) + (size_t)qg * 128 + wv * 32;

  // Y frags (B-operand of S^T): lane needs Y[q=l32][d=16mi+8hi+j]
  bf16x8 Y[4];
#pragma unroll
  for (int mi = 0; mi < 4; ++mi)
    Y[mi] = *(const bf16x8*)(y + (rowq + l32) * DD + mi * 16 + hi * 8);
  const float qbl = qb[rowq + l32];

  // staging: key sxr -> LDS row tau(sxr); V: [d][key] rows of 40
  const int sxr = tid >> 3, sxc = (tid & 7) * 8;
  const int g = sxr >> 2;
  const int taur = (sxr & 3) + 4 * ((g & 4) | ((g & 1) << 1) | ((g >> 1) & 1));
  const int svd = tid >> 2, svc = (tid & 3) * 8;
  const __hip_bfloat16* gx = x + ((size_t)b * SS + koff + sxr) * DD + sxc;
  const __hip_bfloat16* gv = xT + ((size_t)b * DD + svd) * SS + koff + svc;
  const float* kbp = kb + (size_t)b * SS + koff + hi * 8;

  // prologue: tile 0 -> buf 0; tile 1 -> regs
  bf16x8 nx = *(const bf16x8*)gx;
  bf16x8 nv = *(const bf16x8*)gv;
  *(bf16x8*)(&xs[0][taur * 72 + sxc]) = nx;
  *(bf16x8*)(&vsm[0][svd * 40 + svc]) = nv;
  nx = *(const bf16x8*)(gx + 32 * DD);
  nv = *(const bf16x8*)(gv + 32);
  __syncthreads();

  f32x16 O0, O1;
#pragma unroll
  for (int r = 0; r < 16; ++r) { O0[r] = 0.f; O1[r] = 0.f; }
  float lp = 0.f;

  for (int kt = 0; kt < kspl; kt += 32) {
    const int p = (kt >> 5) & 1, np = p ^ 1;
    if (kt + 32 < kspl) {
      *(bf16x8*)(&xs[np][taur * 72 + sxc]) = nx;
      *(bf16x8*)(&vsm[np][svd * 40 + svc]) = nv;
      if (kt + 64 < kspl) {
        nx = *(const bf16x8*)(gx + (size_t)(kt + 64) * DD);
        nv = *(const bf16x8*)(gv + (kt + 64));
      }
    }
    // kb for this tile (L2): reg r <-> key 8hi+(r&7)+16(r>>3)
    const f32x4 kb0a = *(const f32x4*)(kbp + kt);
    const f32x4 kb0b = *(const f32x4*)(kbp + kt + 4);
    const f32x4 kb1a = *(const f32x4*)(kbp + kt + 16);
    const f32x4 kb1b = *(const f32x4*)(kbp + kt + 20);

    // X A-frags: row l32 (tau-permuted keys), cols 16mi+8hi+j
    const bf16x8 A0 = *(const bf16x8*)(&xs[p][l32 * 72 + hi * 8]);
    const bf16x8 A1 = *(const bf16x8*)(&xs[p][l32 * 72 + 16 + hi * 8]);
    const bf16x8 A2 = *(const bf16x8*)(&xs[p][l32 * 72 + 32 + hi * 8]);
    const bf16x8 A3 = *(const bf16x8*)(&xs[p][l32 * 72 + 48 + hi * 8]);

    f32x16 S;
#pragma unroll
    for (int r = 0; r < 16; ++r) S[r] = 0.f;
    S = mfma32(A0, Y[0], S);
    S = mfma32(A1, Y[1], S);
    S = mfma32(A2, Y[2], S);
    S = mfma32(A3, Y[3], S);

    float pv[16];
#pragma unroll
    for (int r = 0; r < 16; ++r) {
      const float kv = (r < 4) ? kb0a[r & 3]
                     : (r < 8) ? kb0b[r & 3]
                     : (r < 12) ? kb1a[r & 3] : kb1b[r & 3];
      pv[r] = __builtin_amdgcn_exp2f(fmaf(S[r], CSCALE, qbl + kv));
    }
    // row-sum partial (this lane's 16 keys of its query)
    {
      float s0 = (pv[0]+pv[1]) + (pv[2]+pv[3]);
      float s1 = (pv[4]+pv[5]) + (pv[6]+pv[7]);
      float s2 = (pv[8]+pv[9]) + (pv[10]+pv[11]);
      float s3 = (pv[12]+pv[13]) + (pv[14]+pv[15]);
      lp += (s0 + s1) + (s2 + s3);
    }
    // PV A-frags: C-reg order IS operand order (tau construction)
    u32x4 R0, R1;
    R0[0] = pack2(pv[0], pv[1]);  R0[1] = pack2(pv[2], pv[3]);
    R0[2] = pack2(pv[4], pv[5]);  R0[3] = pack2(pv[6], pv[7]);
    R1[0] = pack2(pv[8], pv[9]);  R1[1] = pack2(pv[10], pv[11]);
    R1[2] = pack2(pv[12], pv[13]); R1[3] = pack2(pv[14], pv[15]);
    bf16x8 Pf0, Pf1;
    __builtin_memcpy(&Pf0, &R0, 16);
    __builtin_memcpy(&Pf1, &R1, 16);

    // V B-frags: col d = l32+32md, rows keys 16mk+8hi+j
    const bf16x8 V00 = *(const bf16x8*)(&vsm[p][l32 * 40 + hi * 8]);
    const bf16x8 V10 = *(const bf16x8*)(&vsm[p][l32 * 40 + 16 + hi * 8]);
    const bf16x8 V01 = *(const bf16x8*)(&vsm[p][(l32 + 32) * 40 + hi * 8]);
    const bf16x8 V11 = *(const bf16x8*)(&vsm[p][(l32 + 32) * 40 + 16 + hi * 8]);

    O0 = mfma32(Pf0, V00, O0);
    O0 = mfma32(Pf1, V10, O0);
    O1 = mfma32(Pf0, V01, O1);
    O1 = mfma32(Pf1, V11, O1);

    __syncthreads();
  }

  // merge l across hi halves (lane l and l^32 hold same query)
  lp += __shfl_xor(lp, 32, 64);
  const size_t NP = (size_t)SS * 8;
  if (hi == 0) lpart[(size_t)ks * NP + rowq + l32] = lp;

  // O write: lane = d-col (l32 + 32md), reg = query (r&3)+8*(r>>2)+4hi
  float* Op = Opart + ((size_t)ks * NP + rowq) * 64;
#pragma unroll
  for (int r = 0; r < 16; ++r) {
    const int qrow = (r & 3) + 8 * (r >> 2) + 4 * hi;
    Op[(size_t)qrow * 64 + l32]      = O0[r];
    Op[(size_t)qrow * 64 + 32 + l32] = O1[r];
  }
}

// ---------------- combine: merge splits, normalize, out-projection ---------
// XCD-aligned (batch=blk&7) and h-split x2 (hh=blk>>10) for 16 waves/CU.
__global__ __launch_bounds__(128) void combine_kernel(
    const float* __restrict__ Opart, const float* __restrict__ lpart,
    const __hip_bfloat16* __restrict__ wvT, const void* __restrict__ bv_raw,
    void* __restrict__ out_raw, const int* __restrict__ flag, int nspl) {
  const int tid = threadIdx.x;
  const int wv = tid >> 6, lane = tid & 63;
  const int l16 = lane & 15, quad = lane >> 4;
  const int bb = blockIdx.x & 7;                 // batch -> writer XCD
  const int gg = (blockIdx.x >> 3) & 127;        // 0..127 within batch
  const int hh = blockIdx.x >> 10;               // h-half: 0 or 1
  const size_t q0 = ((size_t)bb << 12) + (size_t)gg * 32 + (size_t)wv * 16;
  const int isF32 = *flag;
  const size_t NP = (size_t)SS * 8;   // 32768 queries per split

  float lsum = 0.f;
  for (int s = 0; s < nspl; ++s) lsum += lpart[(size_t)s * NP + q0 + l16];
  const float linv = (lsum > 0.f) ? 1.0f / lsum : 0.f;

  float vlo[8], vhi[8];
#pragma unroll
  for (int j = 0; j < 8; ++j) { vlo[j] = 0.f; vhi[j] = 0.f; }
  for (int s = 0; s < nspl; ++s) {
    const float* p0 = Opart + ((size_t)s * NP + q0 + l16) * 64 + quad * 8;
#pragma unroll
    for (int j = 0; j < 8; j += 4) {
      const float4 a = *(const float4*)(p0 + j);
      vlo[j]   += a.x; vlo[j+1] += a.y; vlo[j+2] += a.z; vlo[j+3] += a.w;
      const float4 c = *(const float4*)(p0 + 32 + j);
      vhi[j]   += c.x; vhi[j+1] += c.y; vhi[j+2] += c.z; vhi[j+3] += c.w;
    }
  }
  u32x4 Rlo, Rhi;
#pragma unroll
  for (int j = 0; j < 4; ++j) {
    Rlo[j] = pack2(vlo[2*j] * linv, vlo[2*j+1] * linv);
    Rhi[j] = pack2(vhi[2*j] * linv, vhi[2*j+1] * linv);
  }
  bf16x8 Alo, Ahi;
  __builtin_memcpy(&Alo, &Rlo, 16);
  __builtin_memcpy(&Ahi, &Rhi, 16);

  float* outf = (float*)out_raw;
  __hip_bfloat16* outb = (__hip_bfloat16*)out_raw;
  const int ht0 = hh * 16;
#pragma unroll 4
  for (int ht = ht0; ht < ht0 + 16; ++ht) {
    const __hip_bfloat16* wp = wvT + (size_t)(ht * 16 + l16) * DD + quad * 8;
    const bf16x8 Wlo = *(const bf16x8*)wp;
    const bf16x8 Whi = *(const bf16x8*)(wp + 32);
    f32x4 C = (f32x4){0.f, 0.f, 0.f, 0.f};
    C = mfma16(Alo, Wlo, C);
    C = mfma16(Ahi, Whi, C);
    const float bvv = loadf(bv_raw, ht * 16 + l16, isF32);
#pragma unroll
    for (int r = 0; r < 4; ++r) {
      const size_t oidx = (q0 + quad * 4 + r) * HH + ht * 16 + l16;
      const float val = C[r] + bvv;
      if (isF32) outf[oidx] = val;
      else       outb[oidx] = __float2bfloat16(val);
    }
  }
}

// ---------------- attn: R10 fallback (single pass, used if ws too small) ---
__global__ __launch_bounds__(256) void attn_kernel(
    const __hip_bfloat16* __restrict__ x,
    const __hip_bfloat16* __restrict__ y,
    const float* __restrict__ qb, const float* __restrict__ kb,
    const __hip_bfloat16* __restrict__ xT,
    const __hip_bfloat16* __restrict__ wvT,
    const void* __restrict__ bv_raw,
    void* __restrict__ out_raw, const int* __restrict__ flag) {
  __shared__ __hip_bfloat16 xs[2][32 * 72];
  __shared__ __hip_bfloat16 vsm[2][64 * 40];
  __shared__ float kbl[SS];
  const int tid = threadIdx.x;
  const int wv = tid >> 6, lane = tid & 63;
  const int l16 = lane & 15, quad = lane >> 4;
  const int b = blockIdx.x & 7;
  const int qt = (blockIdx.x >> 3) * 4 + wv;
  const size_t rowq = ((size_t)b << 12) + ((size_t)qt << 4);
  const int isF32 = *flag;

  const __hip_bfloat16* xb  = x  + ((size_t)b * SS) * DD;
  const __hip_bfloat16* xTb = xT + ((size_t)b * DD) * SS;
  const float* kbb = kb + ((size_t)b * SS);

  const __hip_bfloat16* yp = y + (rowq + l16) * DD + quad * 8;
  const bf16x8 Ylo = *(const bf16x8*)yp;
  const bf16x8 Yhi = *(const bf16x8*)(yp + 32);
  const float qbl = qb[rowq + l16];

  const int sxr = tid >> 3, sxc = (tid & 7) * 8;
  const int taur = (sxr & 3) + ((sxr >> 3) << 2) + (((sxr >> 2) & 1) << 4);
  const int svd = tid >> 2, svc = (tid & 3) * 8;
  const __hip_bfloat16* gx = xb + (size_t)sxr * DD + sxc;
  const __hip_bfloat16* gv = xTb + (size_t)svd * SS + svc;

#pragma unroll
  for (int j = 0; j < 4; ++j) {
    const int c = j * 256 + tid;
    *(f32x4*)(&kbl[c * 4]) = *(const f32x4*)(kbb + c * 4);
  }

  bf16x8 nx = *(const bf16x8*)gx;
  bf16x8 nv = *(const bf16x8*)gv;
  *(bf16x8*)(&xs[0][taur * 72 + sxc]) = nx;
  *(bf16x8*)(&vsm[0][svd * 40 + svc]) = nv;
  nx = *(const bf16x8*)(gx + 32 * DD);
  nv = *(const bf16x8*)(gv + 32);
  __syncthreads();

  bf16x8 onesb;
#pragma unroll
  for (int j = 0; j < 8; ++j) onesb[j] = (__bf16)1.0f;

  f32x4 O[4];
#pragma unroll
  for (int n = 0; n < 4; ++n) O[n] = (f32x4){0.f, 0.f, 0.f, 0.f};
  f32x4 Ol = (f32x4){0.f, 0.f, 0.f, 0.f};

  for (int kt = 0; kt < SS; kt += 32) {
    const int p = (kt >> 5) & 1, np = p ^ 1;
    if (kt + 32 < SS) {
      *(bf16x8*)(&xs[np][taur * 72 + sxc]) = nx;
      *(bf16x8*)(&vsm[np][svd * 40 + svc]) = nv;
      if (kt + 64 < SS) {
        nx = *(const bf16x8*)(gx + (size_t)(kt + 64) * DD);
        nv = *(const bf16x8*)(gv + (kt + 64));
      }
    }
    const bf16x8 B00 = *(const bf16x8*)(&xs[p][l16 * 72 + quad * 8]);
    const bf16x8 B01 = *(const bf16x8*)(&xs[p][l16 * 72 + 32 + quad * 8]);
    const bf16x8 B10 = *(const bf16x8*)(&xs[p][(16 + l16) * 72 + quad * 8]);
    const bf16x8 B11 = *(const bf16x8*)(&xs[p][(16 + l16) * 72 + 32 + quad * 8]);
    const bf16x8 V0 = *(const bf16x8*)(&vsm[p][l16 * 40 + quad * 8]);
    const bf16x8 V1 = *(const bf16x8*)(&vsm[p][(16 + l16) * 40 + quad * 8]);
    const bf16x8 V2 = *(const bf16x8*)(&vsm[p][(32 + l16) * 40 + quad * 8]);
    const bf16x8 V3 = *(const bf16x8*)(&vsm[p][(48 + l16) * 40 + quad * 8]);

    f32x4 S0 = (f32x4){0.f, 0.f, 0.f, 0.f};
    f32x4 S1 = (f32x4){0.f, 0.f, 0.f, 0.f};
    S0 = mfma16(B00, Ylo, S0);
    S0 = mfma16(B01, Yhi, S0);
    S1 = mfma16(B10, Ylo, S1);
    S1 = mfma16(B11, Yhi, S1);

    const f32x4 kb0 = *(const f32x4*)(&kbl[kt + quad * 8]);
    const f32x4 kb1 = *(const f32x4*)(&kbl[kt + quad * 8 + 4]);

    float p0[4], p1[4];
#pragma unroll
    for (int r = 0; r < 4; ++r) {
      p0[r] = __builtin_amdgcn_exp2f(fmaf(S0[r], CSCALE, qbl + kb0[r]));
      p1[r] = __builtin_amdgcn_exp2f(fmaf(S1[r], CSCALE, qbl + kb1[r]));
    }
    u32x4 R;
    R[0] = pack2(p0[0], p0[1]);
    R[1] = pack2(p0[2], p0[3]);
    R[2] = pack2(p1[0], p1[1]);
    R[3] = pack2(p1[2], p1[3]);
    bf16x8 Pf;
    __builtin_memcpy(&Pf, &R, 16);

    O[0] = mfma16(Pf, V0, O[0]);
    O[1] = mfma16(Pf, V1, O[1]);
    O[2] = mfma16(Pf, V2, O[2]);
    O[3] = mfma16(Pf, V3, O[3]);
    Ol = mfma16(Pf, onesb, Ol);

    __syncthreads();
  }

  float inv_l[4];
#pragma unroll
  for (int r = 0; r < 4; ++r)
    inv_l[r] = (Ol[r] > 0.f) ? 1.0f / Ol[r] : 0.f;
  __hip_bfloat16* pl = &xs[0][0] + wv * 1152;
#pragma unroll
  for (int n = 0; n < 4; ++n)
#pragma unroll
    for (int r = 0; r < 4; ++r) {
      const int row = quad * 4 + r;
      pl[row * 72 + n * 16 + l16] = __float2bfloat16(O[n][r] * inv_l[r]);
    }
  __syncthreads();
  const bf16x8 Alo = *(const bf16x8*)(pl + l16 * 72 + quad * 8);
  const bf16x8 Ahi = *(const bf16x8*)(pl + l16 * 72 + 32 + quad * 8);

  float* outf = (float*)out_raw;
  __hip_bfloat16* outb = (__hip_bfloat16*)out_raw;
#pragma unroll 4
  for (int ht = 0; ht < 32; ++ht) {
    const __hip_bfloat16* wp = wvT + (size_t)(ht * 16 + l16) * DD + quad * 8;
    const bf16x8 Wlo = *(const bf16x8*)wp;
    const bf16x8 Whi = *(const bf16x8*)(wp + 32);
    f32x4 C = (f32x4){0.f, 0.f, 0.f, 0.f};
    C = mfma16(Alo, Wlo, C);
    C = mfma16(Ahi, Whi, C);
    const float bvv = loadf(bv_raw, ht * 16 + l16, isF32);
#pragma unroll
    for (int r = 0; r < 4; ++r) {
      const size_t oidx = (rowq + quad * 4 + r) * HH + ht * 16 + l16;
      const float val = C[r] + bvv;
      if (isF32) outf[oidx] = val;
      else       outb[oidx] = __float2bfloat16(val);
    }
  }
}

// ---------------- launcher --------------------------------------------------
extern "C" void kernel_launch(void* const* d_in, const int* in_sizes, int n_in,
                              void* d_out, int out_size, void* d_ws,
                              size_t ws_size, hipStream_t stream) {
  char* ws = (char*)d_ws;
  int*   flag = (int*)(ws + 0);
  __hip_bfloat16* MT = (__hip_bfloat16*)(ws + 1024);       // 8 KB
  float* u    = (float*)(ws + 9216);
  float* w_   = (float*)(ws + 9728);
  float* c_   = (float*)(ws + 10240);
  __hip_bfloat16* wvT = (__hip_bfloat16*)(ws + 32768);     // 64 KB
  __hip_bfloat16* xc  = (__hip_bfloat16*)(ws + 131072);    // 4 MB
  __hip_bfloat16* y   = (__hip_bfloat16*)(ws + 4325376);   // 4 MB
  float* qb = (float*)(ws + 8519680);                       // 128 KB
  float* kb = (float*)(ws + 8650752);                       // 128 KB
  __hip_bfloat16* xT = (__hip_bfloat16*)(ws + 8781824);    // 4 MB
  float* Opart = (float*)(ws + 16777216);                   // up to 32 MB
  const size_t NP = (size_t)SS * 8;
  const size_t need4 = 16777216UL + 4UL * NP * 64 * 4 + 4UL * NP * 4;  // ~50.9 MB
  const size_t need2 = 16777216UL + 2UL * NP * 64 * 4 + 2UL * NP * 4;  // ~33.8 MB

  prep_kernel<<<81, 256, 0, stream>>>(d_in[1], d_in[3], d_in[5], d_in[2],
                                      d_in[4], MT, u, w_, c_, wvT, flag);
  proj_kernel<<<512, 256, 0, stream>>>(d_in[0], MT, u, w_, c_, xc, y, qb, kb,
                                       xT, flag);
  if (ws_size >= need4) {
    float* lpart = (float*)(ws + 16777216 + 4UL * NP * 64 * 4);
    attn_split<<<1024, 256, 0, stream>>>(xc, y, qb, kb, xT, Opart, lpart, 2);
    combine_kernel<<<2048, 128, 0, stream>>>(Opart, lpart, wvT, d_in[6], d_out,
                                             flag, 4);
  } else if (ws_size >= need2) {
    float* lpart = (float*)(ws + 16777216 + 2UL * NP * 64 * 4);
    attn_split<<<512, 256, 0, stream>>>(xc, y, qb, kb, xT, Opart, lpart, 1);
    combine_kernel<<<2048, 128, 0, stream>>>(Opart, lpart, wvT, d_in[6], d_out,
                                             flag, 2);
  } else {
    attn_kernel<<<512, 256, 0, stream>>>(xc, y, qb, kb, xT, wvT, d_in[6],
                                         d_out, flag);
  }
}

// Round 10
// 183.939 us; speedup vs baseline: 1.4556x; 1.0362x over previous
//
#include <hip/hip_runtime.h>
#include <hip/hip_bf16.h>
#include <math.h>

// B=8, S=4096, D_IN=64, H=512 single-head attention, fp32 I/O (dtype-probed).
// scores = x (Wq Wk^T) x^T / sqrt(H); out = softmax(scores) x Wv + bv.
// Folded biases: qb[s]=x_s·(Wq bk)+bq·bk, kb[t]=x_t·(Wk bq); +bv passes thru.
// R17: two mechanism-backed trims.
//  attn (VALUBusy 60% = top pipe): (a) qb cancels: exp2(S+qb+kb) =
//  2^qb*exp2(S+kb), per-query factor cancels in O/l -> dropped from loop
//  (-16 add/iter; bit-identical for zero biases). (b) row-sum via 2x
//  mfma32(Pf,ones) into Ol[16] instead of 15-add VALU tree + shfl (matrix
//  pipe at 22% absorbs it; VALU -30cyc/iter).
//  combine: R16's h-split re-read partials twice (67MB) - null explained.
//  New: 1 block/32 queries (1024x256), partials read ONCE, merged into LDS
//  pa[32][72], 4 waves split (q-half x h-half) for out-proj.

#define SS 4096
#define DD 64
#define HH 512

#define CSCALE ((float)(1.4426950408889634 * 0.04419417382415922))

typedef __bf16 bf16x8 __attribute__((ext_vector_type(8)));
typedef float  f32x4  __attribute__((ext_vector_type(4)));
typedef float  f32x16 __attribute__((ext_vector_type(16)));
typedef unsigned int u32x4 __attribute__((ext_vector_type(4)));

__device__ __forceinline__ float b2f(__hip_bfloat16 v) { return __bfloat162float(v); }

__device__ __forceinline__ f32x4 mfma16(bf16x8 a, bf16x8 b, f32x4 c) {
  return __builtin_amdgcn_mfma_f32_16x16x32_bf16(a, b, c, 0, 0, 0);
}
__device__ __forceinline__ f32x16 mfma32(bf16x8 a, bf16x8 b, f32x16 c) {
  return __builtin_amdgcn_mfma_f32_32x32x16_bf16(a, b, c, 0, 0, 0);
}

__device__ __forceinline__ unsigned pack2(float a, float b) {
  float2 f2; f2.x = a; f2.y = b;
  __hip_bfloat162 h2 = __float22bfloat162_rn(f2);   // a in low 16
  unsigned u; __builtin_memcpy(&u, &h2, 4);
  return u;
}

__device__ __forceinline__ float loadf(const void* p, size_t i, int isF32) {
  return isF32 ? ((const float*)p)[i] : b2f(((const __hip_bfloat16*)p)[i]);
}
__device__ __forceinline__ void load8f(const void* p, size_t i, int isF32, float* o) {
  if (isF32) {
    const float4 a = *(const float4*)((const float*)p + i);
    const float4 b = *(const float4*)((const float*)p + i + 4);
    o[0]=a.x; o[1]=a.y; o[2]=a.z; o[3]=a.w; o[4]=b.x; o[5]=b.y; o[6]=b.z; o[7]=b.w;
  } else {
    const bf16x8 v = *(const bf16x8*)((const __hip_bfloat16*)p + i);
#pragma unroll
    for (int k = 0; k < 8; ++k) { __hip_bfloat16 h; __builtin_memcpy(&h, ((const unsigned short*)&v) + k, 2); o[k] = b2f(h); }
  }
}

// per-wave dtype probe (lane 0..63), returns 1 if Wq looks fp32
__device__ __forceinline__ int probe_f32(const void* Wq, int lane) {
  const unsigned short* h = (const unsigned short*)Wq;
  unsigned int bits = ((unsigned int)h[lane * 2]) << 16;
  float v; __builtin_memcpy(&v, &bits, 4);
  v = fabsf(v);
  if (!isfinite(v) || v > 1e10f) v = 1e10f;
  for (int off = 1; off < 64; off <<= 1) v = fmaxf(v, __shfl_xor(v, off, 64));
  return (v > 1e6f) ? 1 : 0;
}

// ---------------- prep: MT=(Wq Wk^T)^T bf16, u, w, c, wvT, flag ------------
__global__ __launch_bounds__(256) void prep_kernel(
    const void* __restrict__ Wq, const void* __restrict__ Wk,
    const void* __restrict__ Wv, const void* __restrict__ bq,
    const void* __restrict__ bk, __hip_bfloat16* __restrict__ MT,
    float* __restrict__ u, float* __restrict__ w_, float* __restrict__ c_,
    __hip_bfloat16* __restrict__ wvT, int* __restrict__ flag) {
  const int t = threadIdx.x, blk = blockIdx.x;
  __shared__ int fS;
  if (t < 64) { const int f = probe_f32(Wq, t); if (t == 0) fS = f; }
  __syncthreads();
  const int isF32 = fS;
  if (blk < 64) {
    __shared__ float red[256];
    const int i = blk, j = t >> 2, part = t & 3;
    float acc = 0.f, aq[8], ak[8];
    for (int c = 0; c < 16; ++c) {
      load8f(Wq, (size_t)i * HH + part * 128 + c * 8, isF32, aq);
      load8f(Wk, (size_t)j * HH + part * 128 + c * 8, isF32, ak);
#pragma unroll
      for (int k = 0; k < 8; ++k) acc = fmaf(aq[k], ak[k], acc);
    }
    red[t] = acc;
    __syncthreads();
    if (t < 64)
      MT[t * 64 + i] = __float2bfloat16(red[t*4] + red[t*4+1] + red[t*4+2] + red[t*4+3]);
  } else if (blk == 64) {
    __shared__ float pu[256], pw[256], pc[64];
    const int i = t & 63, part = t >> 6;
    float au = 0.f, aw = 0.f, v1[8], v2[8];
    for (int c = 0; c < 16; ++c) {
      load8f(Wq, (size_t)i * HH + part * 128 + c * 8, isF32, v1);
      load8f(bk, part * 128 + c * 8, isF32, v2);
#pragma unroll
      for (int k = 0; k < 8; ++k) au = fmaf(v1[k], v2[k], au);
      load8f(Wk, (size_t)i * HH + part * 128 + c * 8, isF32, v1);
      load8f(bq, part * 128 + c * 8, isF32, v2);
#pragma unroll
      for (int k = 0; k < 8; ++k) aw = fmaf(v1[k], v2[k], aw);
    }
    pu[t] = au; pw[t] = aw;
    if (t < 64) {
      float s = 0.f;
      for (int e = 0; e < 8; ++e)
        s = fmaf(loadf(bq, t * 8 + e, isF32), loadf(bk, t * 8 + e, isF32), s);
      pc[t] = s;
    }
    __syncthreads();
    if (t < 64) {
      u[t]  = pu[t] + pu[t+64] + pu[t+128] + pu[t+192];
      w_[t] = pw[t] + pw[t+64] + pw[t+128] + pw[t+192];
    }
    if (t == 0) {
      float s = 0.f;
      for (int e = 0; e < 64; ++e) s += pc[e];
      *c_ = s;
      *flag = isF32;                      // publish for proj/attn/combine
    }
  } else {
    const int base = (blk - 65) * 2048 + t;
    for (int r = 0; r < 8; ++r) {
      const int e = base + r * 256;          // e = h*64 + d
      const int h = e >> 6, d = e & 63;
      wvT[e] = __float2bfloat16(loadf(Wv, (size_t)d * HH + h, isF32));
    }
  }
}

// ---------------- proj: xc, y = x*M (MFMA), qb/kb, xT (vectorized) ---------
__global__ __launch_bounds__(256) void proj_kernel(
    const void* __restrict__ xraw, const __hip_bfloat16* __restrict__ MT,
    const float* __restrict__ u, const float* __restrict__ w_,
    const float* __restrict__ c_, __hip_bfloat16* __restrict__ xc,
    __hip_bfloat16* __restrict__ y, float* __restrict__ qb,
    float* __restrict__ kb, __hip_bfloat16* __restrict__ xT,
    const int* __restrict__ flag) {
  __shared__ __hip_bfloat16 xs[64 * 72];
  __shared__ __hip_bfloat16 Ms[64 * 72];   // MT staged: Ms[ycol][d]
  __shared__ __hip_bfloat16 st[64 * 72];   // staging: y rows, then xT rows
  __shared__ float us[64], wl[64];
  __shared__ float cs;

  const int t = threadIdx.x;
  const int isF32 = *flag;
  {
    const int r = t >> 2, cb = (t & 3) * 16;
    *(bf16x8*)(&Ms[r * 72 + cb])     = *(const bf16x8*)(MT + r * 64 + cb);
    *(bf16x8*)(&Ms[r * 72 + cb + 8]) = *(const bf16x8*)(MT + r * 64 + cb + 8);
  }
  if (t < 64) { us[t] = u[t]; wl[t] = w_[t]; }
  if (t == 0) cs = *c_;

  const int b = blockIdx.x & 7;
  const int sbase = (blockIdx.x >> 3) * 64;
  const int rbase = b * SS + sbase;

  for (int i = 0; i < 2; ++i) {
    const int e = i * 256 + t;
    const int row = e >> 3, col = (e & 7) * 8;
    float v[8];
    load8f(xraw, (size_t)(rbase + row) * DD + col, isF32, v);
    __hip_bfloat16* dp = xs + row * 72 + col;
#pragma unroll
    for (int k = 0; k < 8; ++k) dp[k] = __float2bfloat16(v[k]);
  }
  __syncthreads();

  const int wv = t >> 6, lane = t & 63;
  const int l16 = lane & 15, quad = lane >> 4;
  // y tile: wave = 16 rows; A[m=row][k=d]
  const bf16x8 A0 = *(const bf16x8*)(&xs[(wv * 16 + l16) * 72 + quad * 8]);
  const bf16x8 A1 = *(const bf16x8*)(&xs[(wv * 16 + l16) * 72 + 32 + quad * 8]);
  float yC[4][4];
#pragma unroll
  for (int nt = 0; nt < 4; ++nt) {
    const bf16x8 B0 = *(const bf16x8*)(&Ms[(nt * 16 + l16) * 72 + quad * 8]);
    const bf16x8 B1 = *(const bf16x8*)(&Ms[(nt * 16 + l16) * 72 + 32 + quad * 8]);
    f32x4 C = (f32x4){0.f, 0.f, 0.f, 0.f};
    C = mfma16(A0, B0, C);
    C = mfma16(A1, B1, C);
#pragma unroll
    for (int r = 0; r < 4; ++r) yC[nt][r] = C[r];
  }

  // qb/kb: 4 threads per q-row (t>>2 = q, t&3 = d-quarter), shfl reduce
  {
    const int q = t >> 2, pp = (t & 3) * 16;
    float qa = 0.f, ka = 0.f;
#pragma unroll
    for (int dd = 0; dd < 16; ++dd) {
      const int d = pp + dd;
      const float xv = b2f(xs[q * 72 + d]);
      qa = fmaf(xv, us[d], qa);
      ka = fmaf(xv, wl[d], ka);
    }
    qa += __shfl_xor(qa, 1, 64); qa += __shfl_xor(qa, 2, 64);
    ka += __shfl_xor(ka, 1, 64); ka += __shfl_xor(ka, 2, 64);
    if ((t & 3) == 0) {
      qb[rbase + q] = (qa + cs) * CSCALE;
      kb[rbase + q] = ka * CSCALE;
    }
  }

  // xc write (vec, from xs)
  for (int i = 0; i < 2; ++i) {
    const int e = i * 256 + t;
    const int row = e >> 3, col = (e & 7) * 8;
    *(bf16x8*)(xc + (size_t)(rbase + row) * DD + col) = *(const bf16x8*)(xs + row * 72 + col);
  }

  // stage y in st (scalar LDS), then vectorized global write
#pragma unroll
  for (int nt = 0; nt < 4; ++nt)
#pragma unroll
    for (int r = 0; r < 4; ++r)
      st[(wv * 16 + quad * 4 + r) * 72 + nt * 16 + l16] = __float2bfloat16(yC[nt][r]);
  __syncthreads();
  {
    const int r = t >> 2, cb = (t & 3) * 16;
    *(bf16x8*)(y + (size_t)(rbase + r) * DD + cb)     = *(const bf16x8*)(&st[r * 72 + cb]);
    *(bf16x8*)(y + (size_t)(rbase + r) * DD + cb + 8) = *(const bf16x8*)(&st[r * 72 + cb + 8]);
  }
  __syncthreads();   // all reads of st done before transpose reuse

  // stage xT rows in st: st[d*72 + s] = xs[s*72 + d], then vec write
  {
    const int d = t >> 2, sc = (t & 3) * 16;
#pragma unroll
    for (int k = 0; k < 16; ++k)
      st[d * 72 + sc + k] = xs[(sc + k) * 72 + d];
  }
  __syncthreads();
  {
    const int d = t >> 2, sc = (t & 3) * 16;
    __hip_bfloat16* xp = xT + ((size_t)b * DD + d) * SS + sbase + sc;
    *(bf16x8*)(xp)     = *(const bf16x8*)(&st[d * 72 + sc]);
    *(bf16x8*)(xp + 8) = *(const bf16x8*)(&st[d * 72 + sc + 8]);
  }
}

// ---------------- attn_split: 32x32 MFMA flash over a key slice ------------
// grid 8*nspl*32: b=blk&7 (XCD), ks=(blk>>3)&(nspl-1), qg=blk>>(3+lgs).
// Block = 128 queries (4 waves x 32). Writes unnormalized O + row-sums l.
// qb is NOT applied (2^qb factor cancels in O/l); row-sums via mfma-ones.
__global__ __launch_bounds__(256) void attn_split(
    const __hip_bfloat16* __restrict__ x,
    const __hip_bfloat16* __restrict__ y,
    const float* __restrict__ qb, const float* __restrict__ kb,
    const __hip_bfloat16* __restrict__ xT,
    float* __restrict__ Opart, float* __restrict__ lpart, int lgs) {
  __shared__ __hip_bfloat16 xs[2][32 * 72];    // 9.2 KB (X tile, tau-permuted)
  __shared__ __hip_bfloat16 vsm[2][64 * 40];   // 10.2 KB (V tile [d][key])
  const int tid = threadIdx.x;
  const int wv = tid >> 6, lane = tid & 63;
  const int l32 = lane & 31, hi = lane >> 5;
  const int b = blockIdx.x & 7;
  const int nspl = 1 << lgs;
  const int ks = (blockIdx.x >> 3) & (nspl - 1);
  const int qg = blockIdx.x >> (3 + lgs);
  const int kspl = SS >> lgs;
  const int koff = ks * kspl;
  const size_t rowq = ((size_t)b << 12) + (size_t)qg * 128 + wv * 32;

  // Y frags (B-operand of S^T): lane needs Y[q=l32][d=16mi+8hi+j]
  bf16x8 Y[4];
#pragma unroll
  for (int mi = 0; mi < 4; ++mi)
    Y[mi] = *(const bf16x8*)(y + (rowq + l32) * DD + mi * 16 + hi * 8);

  // staging: key sxr -> LDS row tau(sxr); V: [d][key] rows of 40
  const int sxr = tid >> 3, sxc = (tid & 7) * 8;
  const int g = sxr >> 2;
  const int taur = (sxr & 3) + 4 * ((g & 4) | ((g & 1) << 1) | ((g >> 1) & 1));
  const int svd = tid >> 2, svc = (tid & 3) * 8;
  const __hip_bfloat16* gx = x + ((size_t)b * SS + koff + sxr) * DD + sxc;
  const __hip_bfloat16* gv = xT + ((size_t)b * DD + svd) * SS + koff + svc;
  const float* kbp = kb + (size_t)b * SS + koff + hi * 8;

  // prologue: tile 0 -> buf 0; tile 1 -> regs
  bf16x8 nx = *(const bf16x8*)gx;
  bf16x8 nv = *(const bf16x8*)gv;
  *(bf16x8*)(&xs[0][taur * 72 + sxc]) = nx;
  *(bf16x8*)(&vsm[0][svd * 40 + svc]) = nv;
  nx = *(const bf16x8*)(gx + 32 * DD);
  nv = *(const bf16x8*)(gv + 32);
  __syncthreads();

  bf16x8 onesb;
#pragma unroll
  for (int j = 0; j < 8; ++j) onesb[j] = (__bf16)1.0f;

  f32x16 O0, O1, Ol;
#pragma unroll
  for (int r = 0; r < 16; ++r) { O0[r] = 0.f; O1[r] = 0.f; Ol[r] = 0.f; }

  for (int kt = 0; kt < kspl; kt += 32) {
    const int p = (kt >> 5) & 1, np = p ^ 1;
    if (kt + 32 < kspl) {
      *(bf16x8*)(&xs[np][taur * 72 + sxc]) = nx;
      *(bf16x8*)(&vsm[np][svd * 40 + svc]) = nv;
      if (kt + 64 < kspl) {
        nx = *(const bf16x8*)(gx + (size_t)(kt + 64) * DD);
        nv = *(const bf16x8*)(gv + (kt + 64));
      }
    }
    // kb for this tile (L2): reg r <-> key 8hi+(r&7)+16(r>>3)
    const f32x4 kb0a = *(const f32x4*)(kbp + kt);
    const f32x4 kb0b = *(const f32x4*)(kbp + kt + 4);
    const f32x4 kb1a = *(const f32x4*)(kbp + kt + 16);
    const f32x4 kb1b = *(const f32x4*)(kbp + kt + 20);

    // X A-frags: row l32 (tau-permuted keys), cols 16mi+8hi+j
    const bf16x8 A0 = *(const bf16x8*)(&xs[p][l32 * 72 + hi * 8]);
    const bf16x8 A1 = *(const bf16x8*)(&xs[p][l32 * 72 + 16 + hi * 8]);
    const bf16x8 A2 = *(const bf16x8*)(&xs[p][l32 * 72 + 32 + hi * 8]);
    const bf16x8 A3 = *(const bf16x8*)(&xs[p][l32 * 72 + 48 + hi * 8]);

    f32x16 S;
#pragma unroll
    for (int r = 0; r < 16; ++r) S[r] = 0.f;
    S = mfma32(A0, Y[0], S);
    S = mfma32(A1, Y[1], S);
    S = mfma32(A2, Y[2], S);
    S = mfma32(A3, Y[3], S);

    float pv[16];
#pragma unroll
    for (int r = 0; r < 16; ++r) {
      const float kv = (r < 4) ? kb0a[r & 3]
                     : (r < 8) ? kb0b[r & 3]
                     : (r < 12) ? kb1a[r & 3] : kb1b[r & 3];
      pv[r] = __builtin_amdgcn_exp2f(fmaf(S[r], CSCALE, kv));
    }
    // PV A-frags: C-reg order IS operand order (tau construction)
    u32x4 R0, R1;
    R0[0] = pack2(pv[0], pv[1]);  R0[1] = pack2(pv[2], pv[3]);
    R0[2] = pack2(pv[4], pv[5]);  R0[3] = pack2(pv[6], pv[7]);
    R1[0] = pack2(pv[8], pv[9]);  R1[1] = pack2(pv[10], pv[11]);
    R1[2] = pack2(pv[12], pv[13]); R1[3] = pack2(pv[14], pv[15]);
    bf16x8 Pf0, Pf1;
    __builtin_memcpy(&Pf0, &R0, 16);
    __builtin_memcpy(&Pf1, &R1, 16);

    // V B-frags: col d = l32+32md, rows keys 16mk+8hi+j
    const bf16x8 V00 = *(const bf16x8*)(&vsm[p][l32 * 40 + hi * 8]);
    const bf16x8 V10 = *(const bf16x8*)(&vsm[p][l32 * 40 + 16 + hi * 8]);
    const bf16x8 V01 = *(const bf16x8*)(&vsm[p][(l32 + 32) * 40 + hi * 8]);
    const bf16x8 V11 = *(const bf16x8*)(&vsm[p][(l32 + 32) * 40 + 16 + hi * 8]);

    O0 = mfma32(Pf0, V00, O0);
    O0 = mfma32(Pf1, V10, O0);
    O1 = mfma32(Pf0, V01, O1);
    O1 = mfma32(Pf1, V11, O1);
    Ol = mfma32(Pf0, onesb, Ol);   // row-sums (matrix pipe, not VALU)
    Ol = mfma32(Pf1, onesb, Ol);

    __syncthreads();
  }

  const size_t NP = (size_t)SS * 8;
  // lpart: Ol[r] = rowsum for query (r&3)+8(r>>2)+4hi (all l32 identical)
  if (l32 == 0) {
#pragma unroll
    for (int r = 0; r < 16; ++r)
      lpart[(size_t)ks * NP + rowq + (r & 3) + 8 * (r >> 2) + 4 * hi] = Ol[r];
  }

  // O write: lane = d-col (l32 + 32md), reg = query (r&3)+8*(r>>2)+4hi
  float* Op = Opart + ((size_t)ks * NP + rowq) * 64;
#pragma unroll
  for (int r = 0; r < 16; ++r) {
    const int qrow = (r & 3) + 8 * (r >> 2) + 4 * hi;
    Op[(size_t)qrow * 64 + l32]      = O0[r];
    Op[(size_t)qrow * 64 + 32 + l32] = O1[r];
  }
}

// ---------------- combine: merge once into LDS, 4-wave out-projection ------
// grid 1024 x 256: bb=blk&7 (writer XCD), gg=blk>>3 (32-query group).
// Partials read ONCE (R16's h-split read them twice - null explained).
__global__ __launch_bounds__(256) void combine_kernel(
    const float* __restrict__ Opart, const float* __restrict__ lpart,
    const __hip_bfloat16* __restrict__ wvT, const void* __restrict__ bv_raw,
    void* __restrict__ out_raw, const int* __restrict__ flag, int nspl) {
  __shared__ __hip_bfloat16 pa[32 * 72];   // merged+normalized P (bf16)
  __shared__ float lsI[32];
  const int tid = threadIdx.x;
  const int bb = blockIdx.x & 7;
  const int gg = blockIdx.x >> 3;                // 0..127 within batch
  const size_t q0 = ((size_t)bb << 12) + (size_t)gg * 32;
  const int isF32 = *flag;
  const size_t NP = (size_t)SS * 8;

  if (tid < 32) {
    float ls = 0.f;
    for (int s = 0; s < nspl; ++s) ls += lpart[(size_t)s * NP + q0 + tid];
    lsI[tid] = (ls > 0.f) ? 1.0f / ls : 0.f;
  }
  // merge: thread handles query mq = tid>>3, d-seg md = (tid&7)*8
  const int mq = tid >> 3, md = (tid & 7) * 8;
  float acc[8];
#pragma unroll
  for (int j = 0; j < 8; ++j) acc[j] = 0.f;
  for (int s = 0; s < nspl; ++s) {
    const float* pp = Opart + ((size_t)s * NP + q0 + mq) * 64 + md;
    const float4 a = *(const float4*)pp;
    const float4 c = *(const float4*)(pp + 4);
    acc[0] += a.x; acc[1] += a.y; acc[2] += a.z; acc[3] += a.w;
    acc[4] += c.x; acc[5] += c.y; acc[6] += c.z; acc[7] += c.w;
  }
  __syncthreads();            // lsI ready
  {
    const float linv = lsI[mq];
    u32x4 R;
#pragma unroll
    for (int j = 0; j < 4; ++j)
      R[j] = pack2(acc[2*j] * linv, acc[2*j+1] * linv);
    __builtin_memcpy(&pa[mq * 72 + md], &R, 16);
  }
  __syncthreads();            // pa ready

  // out-proj: wave wv -> q-half (wv&1), h-half (wv>>1); 16 ht tiles each
  const int wv = tid >> 6, lane = tid & 63;
  const int l16 = lane & 15, quad = lane >> 4;
  const int qh = wv & 1, hh = wv >> 1;
  const __hip_bfloat16* par = &pa[(qh * 16 + l16) * 72];
  const bf16x8 Alo = *(const bf16x8*)(par + quad * 8);
  const bf16x8 Ahi = *(const bf16x8*)(par + 32 + quad * 8);

  float* outf = (float*)out_raw;
  __hip_bfloat16* outb = (__hip_bfloat16*)out_raw;
  const int ht0 = hh * 16;
#pragma unroll 4
  for (int ht = ht0; ht < ht0 + 16; ++ht) {
    const __hip_bfloat16* wp = wvT + (size_t)(ht * 16 + l16) * DD + quad * 8;
    const bf16x8 Wlo = *(const bf16x8*)wp;
    const bf16x8 Whi = *(const bf16x8*)(wp + 32);
    f32x4 C = (f32x4){0.f, 0.f, 0.f, 0.f};
    C = mfma16(Alo, Wlo, C);
    C = mfma16(Ahi, Whi, C);
    const float bvv = loadf(bv_raw, ht * 16 + l16, isF32);
#pragma unroll
    for (int r = 0; r < 4; ++r) {
      const size_t oidx = (q0 + qh * 16 + quad * 4 + r) * HH + ht * 16 + l16;
      const float val = C[r] + bvv;
      if (isF32) outf[oidx] = val;
      else       outb[oidx] = __float2bfloat16(val);
    }
  }
}

// ---------------- attn: R10 fallback (single pass, used if ws too small) ---
__global__ __launch_bounds__(256) void attn_kernel(
    const __hip_bfloat16* __restrict__ x,
    const __hip_bfloat16* __restrict__ y,
    const float* __restrict__ qb, const float* __restrict__ kb,
    const __hip_bfloat16* __restrict__ xT,
    const __hip_bfloat16* __restrict__ wvT,
    const void* __restrict__ bv_raw,
    void* __restrict__ out_raw, const int* __restrict__ flag) {
  __shared__ __hip_bfloat16 xs[2][32 * 72];
  __shared__ __hip_bfloat16 vsm[2][64 * 40];
  __shared__ float kbl[SS];
  const int tid = threadIdx.x;
  const int wv = tid >> 6, lane = tid & 63;
  const int l16 = lane & 15, quad = lane >> 4;
  const int b = blockIdx.x & 7;
  const int qt = (blockIdx.x >> 3) * 4 + wv;
  const size_t rowq = ((size_t)b << 12) + ((size_t)qt << 4);
  const int isF32 = *flag;

  const __hip_bfloat16* xb  = x  + ((size_t)b * SS) * DD;
  const __hip_bfloat16* xTb = xT + ((size_t)b * DD) * SS;
  const float* kbb = kb + ((size_t)b * SS);

  const __hip_bfloat16* yp = y + (rowq + l16) * DD + quad * 8;
  const bf16x8 Ylo = *(const bf16x8*)yp;
  const bf16x8 Yhi = *(const bf16x8*)(yp + 32);
  const float qbl = qb[rowq + l16];

  const int sxr = tid >> 3, sxc = (tid & 7) * 8;
  const int taur = (sxr & 3) + ((sxr >> 3) << 2) + (((sxr >> 2) & 1) << 4);
  const int svd = tid >> 2, svc = (tid & 3) * 8;
  const __hip_bfloat16* gx = xb + (size_t)sxr * DD + sxc;
  const __hip_bfloat16* gv = xTb + (size_t)svd * SS + svc;

#pragma unroll
  for (int j = 0; j < 4; ++j) {
    const int c = j * 256 + tid;
    *(f32x4*)(&kbl[c * 4]) = *(const f32x4*)(kbb + c * 4);
  }

  bf16x8 nx = *(const bf16x8*)gx;
  bf16x8 nv = *(const bf16x8*)gv;
  *(bf16x8*)(&xs[0][taur * 72 + sxc]) = nx;
  *(bf16x8*)(&vsm[0][svd * 40 + svc]) = nv;
  nx = *(const bf16x8*)(gx + 32 * DD);
  nv = *(const bf16x8*)(gv + 32);
  __syncthreads();

  bf16x8 onesb;
#pragma unroll
  for (int j = 0; j < 8; ++j) onesb[j] = (__bf16)1.0f;

  f32x4 O[4];
#pragma unroll
  for (int n = 0; n < 4; ++n) O[n] = (f32x4){0.f, 0.f, 0.f, 0.f};
  f32x4 Ol = (f32x4){0.f, 0.f, 0.f, 0.f};

  for (int kt = 0; kt < SS; kt += 32) {
    const int p = (kt >> 5) & 1, np = p ^ 1;
    if (kt + 32 < SS) {
      *(bf16x8*)(&xs[np][taur * 72 + sxc]) = nx;
      *(bf16x8*)(&vsm[np][svd * 40 + svc]) = nv;
      if (kt + 64 < SS) {
        nx = *(const bf16x8*)(gx + (size_t)(kt + 64) * DD);
        nv = *(const bf16x8*)(gv + (kt + 64));
      }
    }
    const bf16x8 B00 = *(const bf16x8*)(&xs[p][l16 * 72 + quad * 8]);
    const bf16x8 B01 = *(const bf16x8*)(&xs[p][l16 * 72 + 32 + quad * 8]);
    const bf16x8 B10 = *(const bf16x8*)(&xs[p][(16 + l16) * 72 + quad * 8]);
    const bf16x8 B11 = *(const bf16x8*)(&xs[p][(16 + l16) * 72 + 32 + quad * 8]);
    const bf16x8 V0 = *(const bf16x8*)(&vsm[p][l16 * 40 + quad * 8]);
    const bf16x8 V1 = *(const bf16x8*)(&vsm[p][(16 + l16) * 40 + quad * 8]);
    const bf16x8 V2 = *(const bf16x8*)(&vsm[p][(32 + l16) * 40 + quad * 8]);
    const bf16x8 V3 = *(const bf16x8*)(&vsm[p][(48 + l16) * 40 + quad * 8]);

    f32x4 S0 = (f32x4){0.f, 0.f, 0.f, 0.f};
    f32x4 S1 = (f32x4){0.f, 0.f, 0.f, 0.f};
    S0 = mfma16(B00, Ylo, S0);
    S0 = mfma16(B01, Yhi, S0);
    S1 = mfma16(B10, Ylo, S1);
    S1 = mfma16(B11, Yhi, S1);

    const f32x4 kb0 = *(const f32x4*)(&kbl[kt + quad * 8]);
    const f32x4 kb1 = *(const f32x4*)(&kbl[kt + quad * 8 + 4]);

    float p0[4], p1[4];
#pragma unroll
    for (int r = 0; r < 4; ++r) {
      p0[r] = __builtin_amdgcn_exp2f(fmaf(S0[r], CSCALE, qbl + kb0[r]));
      p1[r] = __builtin_amdgcn_exp2f(fmaf(S1[r], CSCALE, qbl + kb1[r]));
    }
    u32x4 R;
    R[0] = pack2(p0[0], p0[1]);
    R[1] = pack2(p0[2], p0[3]);
    R[2] = pack2(p1[0], p1[1]);
    R[3] = pack2(p1[2], p1[3]);
    bf16x8 Pf;
    __builtin_memcpy(&Pf, &R, 16);

    O[0] = mfma16(Pf, V0, O[0]);
    O[1] = mfma16(Pf, V1, O[1]);
    O[2] = mfma16(Pf, V2, O[2]);
    O[3] = mfma16(Pf, V3, O[3]);
    Ol = mfma16(Pf, onesb, Ol);

    __syncthreads();
  }

  float inv_l[4];
#pragma unroll
  for (int r = 0; r < 4; ++r)
    inv_l[r] = (Ol[r] > 0.f) ? 1.0f / Ol[r] : 0.f;
  __hip_bfloat16* pl = &xs[0][0] + wv * 1152;
#pragma unroll
  for (int n = 0; n < 4; ++n)
#pragma unroll
    for (int r = 0; r < 4; ++r) {
      const int row = quad * 4 + r;
      pl[row * 72 + n * 16 + l16] = __float2bfloat16(O[n][r] * inv_l[r]);
    }
  __syncthreads();
  const bf16x8 Alo = *(const bf16x8*)(pl + l16 * 72 + quad * 8);
  const bf16x8 Ahi = *(const bf16x8*)(pl + l16 * 72 + 32 + quad * 8);

  float* outf = (float*)out_raw;
  __hip_bfloat16* outb = (__hip_bfloat16*)out_raw;
#pragma unroll 4
  for (int ht = 0; ht < 32; ++ht) {
    const __hip_bfloat16* wp = wvT + (size_t)(ht * 16 + l16) * DD + quad * 8;
    const bf16x8 Wlo = *(const bf16x8*)wp;
    const bf16x8 Whi = *(const bf16x8*)(wp + 32);
    f32x4 C = (f32x4){0.f, 0.f, 0.f, 0.f};
    C = mfma16(Alo, Wlo, C);
    C = mfma16(Ahi, Whi, C);
    const float bvv = loadf(bv_raw, ht * 16 + l16, isF32);
#pragma unroll
    for (int r = 0; r < 4; ++r) {
      const size_t oidx = (rowq + quad * 4 + r) * HH + ht * 16 + l16;
      const float val = C[r] + bvv;
      if (isF32) outf[oidx] = val;
      else       outb[oidx] = __float2bfloat16(val);
    }
  }
}

// ---------------- launcher --------------------------------------------------
extern "C" void kernel_launch(void* const* d_in, const int* in_sizes, int n_in,
                              void* d_out, int out_size, void* d_ws,
                              size_t ws_size, hipStream_t stream) {
  char* ws = (char*)d_ws;
  int*   flag = (int*)(ws + 0);
  __hip_bfloat16* MT = (__hip_bfloat16*)(ws + 1024);       // 8 KB
  float* u    = (float*)(ws + 9216);
  float* w_   = (float*)(ws + 9728);
  float* c_   = (float*)(ws + 10240);
  __hip_bfloat16* wvT = (__hip_bfloat16*)(ws + 32768);     // 64 KB
  __hip_bfloat16* xc  = (__hip_bfloat16*)(ws + 131072);    // 4 MB
  __hip_bfloat16* y   = (__hip_bfloat16*)(ws + 4325376);   // 4 MB
  float* qb = (float*)(ws + 8519680);                       // 128 KB
  float* kb = (float*)(ws + 8650752);                       // 128 KB
  __hip_bfloat16* xT = (__hip_bfloat16*)(ws + 8781824);    // 4 MB
  float* Opart = (float*)(ws + 16777216);                   // up to 32 MB
  const size_t NP = (size_t)SS * 8;
  const size_t need4 = 16777216UL + 4UL * NP * 64 * 4 + 4UL * NP * 4;  // ~50.9 MB
  const size_t need2 = 16777216UL + 2UL * NP * 64 * 4 + 2UL * NP * 4;  // ~33.8 MB

  prep_kernel<<<81, 256, 0, stream>>>(d_in[1], d_in[3], d_in[5], d_in[2],
                                      d_in[4], MT, u, w_, c_, wvT, flag);
  proj_kernel<<<512, 256, 0, stream>>>(d_in[0], MT, u, w_, c_, xc, y, qb, kb,
                                       xT, flag);
  if (ws_size >= need4) {
    float* lpart = (float*)(ws + 16777216 + 4UL * NP * 64 * 4);
    attn_split<<<1024, 256, 0, stream>>>(xc, y, qb, kb, xT, Opart, lpart, 2);
    combine_kernel<<<1024, 256, 0, stream>>>(Opart, lpart, wvT, d_in[6], d_out,
                                             flag, 4);
  } else if (ws_size >= need2) {
    float* lpart = (float*)(ws + 16777216 + 2UL * NP * 64 * 4);
    attn_split<<<512, 256, 0, stream>>>(xc, y, qb, kb, xT, Opart, lpart, 1);
    combine_kernel<<<1024, 256, 0, stream>>>(Opart, lpart, wvT, d_in[6], d_out,
                                             flag, 2);
  } else {
    attn_kernel<<<512, 256, 0, stream>>>(xc, y, qb, kb, xT, wvT, d_in[6],
                                         d_out, flag);
  }
}

// Round 11
// 183.504 us; speedup vs baseline: 1.4590x; 1.0024x over previous
//
#include <hip/hip_runtime.h>
#include <hip/hip_bf16.h>
#include <math.h>

// B=8, S=4096, D_IN=64, H=512 single-head attention, fp32 I/O (dtype-probed).
// scores = x (Wq Wk^T) x^T / sqrt(H); out = softmax(scores) x Wv + bv.
// Folded biases: qb[s]=x_s·(Wq bk)+bq·bk, kb[t]=x_t·(Wk bq); +bv passes thru.
// R18: R17 post-mortem - VALU trim moved counters (VALU 60->49.5, Mfma
// 22->26) but NOT time: attn_split is latency-bound at 4 waves/SIMD (no
// pipe >50%). Lever = occupancy: 8-way key split (grid 2048, 8 blocks/CU,
// ~2x resident waves; same mechanism as R10->R11's 102->73). Partials grow
// to 67MB (ws ~85MB, gated; falls back to proven 4-way if too small).
// Combine handles nspl=8 (+7us BW). Everything else verbatim R17.

#define SS 4096
#define DD 64
#define HH 512

#define CSCALE ((float)(1.4426950408889634 * 0.04419417382415922))

typedef __bf16 bf16x8 __attribute__((ext_vector_type(8)));
typedef float  f32x4  __attribute__((ext_vector_type(4)));
typedef float  f32x16 __attribute__((ext_vector_type(16)));
typedef unsigned int u32x4 __attribute__((ext_vector_type(4)));

__device__ __forceinline__ float b2f(__hip_bfloat16 v) { return __bfloat162float(v); }

__device__ __forceinline__ f32x4 mfma16(bf16x8 a, bf16x8 b, f32x4 c) {
  return __builtin_amdgcn_mfma_f32_16x16x32_bf16(a, b, c, 0, 0, 0);
}
__device__ __forceinline__ f32x16 mfma32(bf16x8 a, bf16x8 b, f32x16 c) {
  return __builtin_amdgcn_mfma_f32_32x32x16_bf16(a, b, c, 0, 0, 0);
}

__device__ __forceinline__ unsigned pack2(float a, float b) {
  float2 f2; f2.x = a; f2.y = b;
  __hip_bfloat162 h2 = __float22bfloat162_rn(f2);   // a in low 16
  unsigned u; __builtin_memcpy(&u, &h2, 4);
  return u;
}

__device__ __forceinline__ float loadf(const void* p, size_t i, int isF32) {
  return isF32 ? ((const float*)p)[i] : b2f(((const __hip_bfloat16*)p)[i]);
}
__device__ __forceinline__ void load8f(const void* p, size_t i, int isF32, float* o) {
  if (isF32) {
    const float4 a = *(const float4*)((const float*)p + i);
    const float4 b = *(const float4*)((const float*)p + i + 4);
    o[0]=a.x; o[1]=a.y; o[2]=a.z; o[3]=a.w; o[4]=b.x; o[5]=b.y; o[6]=b.z; o[7]=b.w;
  } else {
    const bf16x8 v = *(const bf16x8*)((const __hip_bfloat16*)p + i);
#pragma unroll
    for (int k = 0; k < 8; ++k) { __hip_bfloat16 h; __builtin_memcpy(&h, ((const unsigned short*)&v) + k, 2); o[k] = b2f(h); }
  }
}

// per-wave dtype probe (lane 0..63), returns 1 if Wq looks fp32
__device__ __forceinline__ int probe_f32(const void* Wq, int lane) {
  const unsigned short* h = (const unsigned short*)Wq;
  unsigned int bits = ((unsigned int)h[lane * 2]) << 16;
  float v; __builtin_memcpy(&v, &bits, 4);
  v = fabsf(v);
  if (!isfinite(v) || v > 1e10f) v = 1e10f;
  for (int off = 1; off < 64; off <<= 1) v = fmaxf(v, __shfl_xor(v, off, 64));
  return (v > 1e6f) ? 1 : 0;
}

// ---------------- prep: MT=(Wq Wk^T)^T bf16, u, w, c, wvT, flag ------------
__global__ __launch_bounds__(256) void prep_kernel(
    const void* __restrict__ Wq, const void* __restrict__ Wk,
    const void* __restrict__ Wv, const void* __restrict__ bq,
    const void* __restrict__ bk, __hip_bfloat16* __restrict__ MT,
    float* __restrict__ u, float* __restrict__ w_, float* __restrict__ c_,
    __hip_bfloat16* __restrict__ wvT, int* __restrict__ flag) {
  const int t = threadIdx.x, blk = blockIdx.x;
  __shared__ int fS;
  if (t < 64) { const int f = probe_f32(Wq, t); if (t == 0) fS = f; }
  __syncthreads();
  const int isF32 = fS;
  if (blk < 64) {
    __shared__ float red[256];
    const int i = blk, j = t >> 2, part = t & 3;
    float acc = 0.f, aq[8], ak[8];
    for (int c = 0; c < 16; ++c) {
      load8f(Wq, (size_t)i * HH + part * 128 + c * 8, isF32, aq);
      load8f(Wk, (size_t)j * HH + part * 128 + c * 8, isF32, ak);
#pragma unroll
      for (int k = 0; k < 8; ++k) acc = fmaf(aq[k], ak[k], acc);
    }
    red[t] = acc;
    __syncthreads();
    if (t < 64)
      MT[t * 64 + i] = __float2bfloat16(red[t*4] + red[t*4+1] + red[t*4+2] + red[t*4+3]);
  } else if (blk == 64) {
    __shared__ float pu[256], pw[256], pc[64];
    const int i = t & 63, part = t >> 6;
    float au = 0.f, aw = 0.f, v1[8], v2[8];
    for (int c = 0; c < 16; ++c) {
      load8f(Wq, (size_t)i * HH + part * 128 + c * 8, isF32, v1);
      load8f(bk, part * 128 + c * 8, isF32, v2);
#pragma unroll
      for (int k = 0; k < 8; ++k) au = fmaf(v1[k], v2[k], au);
      load8f(Wk, (size_t)i * HH + part * 128 + c * 8, isF32, v1);
      load8f(bq, part * 128 + c * 8, isF32, v2);
#pragma unroll
      for (int k = 0; k < 8; ++k) aw = fmaf(v1[k], v2[k], aw);
    }
    pu[t] = au; pw[t] = aw;
    if (t < 64) {
      float s = 0.f;
      for (int e = 0; e < 8; ++e)
        s = fmaf(loadf(bq, t * 8 + e, isF32), loadf(bk, t * 8 + e, isF32), s);
      pc[t] = s;
    }
    __syncthreads();
    if (t < 64) {
      u[t]  = pu[t] + pu[t+64] + pu[t+128] + pu[t+192];
      w_[t] = pw[t] + pw[t+64] + pw[t+128] + pw[t+192];
    }
    if (t == 0) {
      float s = 0.f;
      for (int e = 0; e < 64; ++e) s += pc[e];
      *c_ = s;
      *flag = isF32;                      // publish for proj/attn/combine
    }
  } else {
    const int base = (blk - 65) * 2048 + t;
    for (int r = 0; r < 8; ++r) {
      const int e = base + r * 256;          // e = h*64 + d
      const int h = e >> 6, d = e & 63;
      wvT[e] = __float2bfloat16(loadf(Wv, (size_t)d * HH + h, isF32));
    }
  }
}

// ---------------- proj: xc, y = x*M (MFMA), qb/kb, xT (vectorized) ---------
__global__ __launch_bounds__(256) void proj_kernel(
    const void* __restrict__ xraw, const __hip_bfloat16* __restrict__ MT,
    const float* __restrict__ u, const float* __restrict__ w_,
    const float* __restrict__ c_, __hip_bfloat16* __restrict__ xc,
    __hip_bfloat16* __restrict__ y, float* __restrict__ qb,
    float* __restrict__ kb, __hip_bfloat16* __restrict__ xT,
    const int* __restrict__ flag) {
  __shared__ __hip_bfloat16 xs[64 * 72];
  __shared__ __hip_bfloat16 Ms[64 * 72];   // MT staged: Ms[ycol][d]
  __shared__ __hip_bfloat16 st[64 * 72];   // staging: y rows, then xT rows
  __shared__ float us[64], wl[64];
  __shared__ float cs;

  const int t = threadIdx.x;
  const int isF32 = *flag;
  {
    const int r = t >> 2, cb = (t & 3) * 16;
    *(bf16x8*)(&Ms[r * 72 + cb])     = *(const bf16x8*)(MT + r * 64 + cb);
    *(bf16x8*)(&Ms[r * 72 + cb + 8]) = *(const bf16x8*)(MT + r * 64 + cb + 8);
  }
  if (t < 64) { us[t] = u[t]; wl[t] = w_[t]; }
  if (t == 0) cs = *c_;

  const int b = blockIdx.x & 7;
  const int sbase = (blockIdx.x >> 3) * 64;
  const int rbase = b * SS + sbase;

  for (int i = 0; i < 2; ++i) {
    const int e = i * 256 + t;
    const int row = e >> 3, col = (e & 7) * 8;
    float v[8];
    load8f(xraw, (size_t)(rbase + row) * DD + col, isF32, v);
    __hip_bfloat16* dp = xs + row * 72 + col;
#pragma unroll
    for (int k = 0; k < 8; ++k) dp[k] = __float2bfloat16(v[k]);
  }
  __syncthreads();

  const int wv = t >> 6, lane = t & 63;
  const int l16 = lane & 15, quad = lane >> 4;
  // y tile: wave = 16 rows; A[m=row][k=d]
  const bf16x8 A0 = *(const bf16x8*)(&xs[(wv * 16 + l16) * 72 + quad * 8]);
  const bf16x8 A1 = *(const bf16x8*)(&xs[(wv * 16 + l16) * 72 + 32 + quad * 8]);
  float yC[4][4];
#pragma unroll
  for (int nt = 0; nt < 4; ++nt) {
    const bf16x8 B0 = *(const bf16x8*)(&Ms[(nt * 16 + l16) * 72 + quad * 8]);
    const bf16x8 B1 = *(const bf16x8*)(&Ms[(nt * 16 + l16) * 72 + 32 + quad * 8]);
    f32x4 C = (f32x4){0.f, 0.f, 0.f, 0.f};
    C = mfma16(A0, B0, C);
    C = mfma16(A1, B1, C);
#pragma unroll
    for (int r = 0; r < 4; ++r) yC[nt][r] = C[r];
  }

  // qb/kb: 4 threads per q-row (t>>2 = q, t&3 = d-quarter), shfl reduce
  {
    const int q = t >> 2, pp = (t & 3) * 16;
    float qa = 0.f, ka = 0.f;
#pragma unroll
    for (int dd = 0; dd < 16; ++dd) {
      const int d = pp + dd;
      const float xv = b2f(xs[q * 72 + d]);
      qa = fmaf(xv, us[d], qa);
      ka = fmaf(xv, wl[d], ka);
    }
    qa += __shfl_xor(qa, 1, 64); qa += __shfl_xor(qa, 2, 64);
    ka += __shfl_xor(ka, 1, 64); ka += __shfl_xor(ka, 2, 64);
    if ((t & 3) == 0) {
      qb[rbase + q] = (qa + cs) * CSCALE;
      kb[rbase + q] = ka * CSCALE;
    }
  }

  // xc write (vec, from xs)
  for (int i = 0; i < 2; ++i) {
    const int e = i * 256 + t;
    const int row = e >> 3, col = (e & 7) * 8;
    *(bf16x8*)(xc + (size_t)(rbase + row) * DD + col) = *(const bf16x8*)(xs + row * 72 + col);
  }

  // stage y in st (scalar LDS), then vectorized global write
#pragma unroll
  for (int nt = 0; nt < 4; ++nt)
#pragma unroll
    for (int r = 0; r < 4; ++r)
      st[(wv * 16 + quad * 4 + r) * 72 + nt * 16 + l16] = __float2bfloat16(yC[nt][r]);
  __syncthreads();
  {
    const int r = t >> 2, cb = (t & 3) * 16;
    *(bf16x8*)(y + (size_t)(rbase + r) * DD + cb)     = *(const bf16x8*)(&st[r * 72 + cb]);
    *(bf16x8*)(y + (size_t)(rbase + r) * DD + cb + 8) = *(const bf16x8*)(&st[r * 72 + cb + 8]);
  }
  __syncthreads();   // all reads of st done before transpose reuse

  // stage xT rows in st: st[d*72 + s] = xs[s*72 + d], then vec write
  {
    const int d = t >> 2, sc = (t & 3) * 16;
#pragma unroll
    for (int k = 0; k < 16; ++k)
      st[d * 72 + sc + k] = xs[(sc + k) * 72 + d];
  }
  __syncthreads();
  {
    const int d = t >> 2, sc = (t & 3) * 16;
    __hip_bfloat16* xp = xT + ((size_t)b * DD + d) * SS + sbase + sc;
    *(bf16x8*)(xp)     = *(const bf16x8*)(&st[d * 72 + sc]);
    *(bf16x8*)(xp + 8) = *(const bf16x8*)(&st[d * 72 + sc + 8]);
  }
}

// ---------------- attn_split: 32x32 MFMA flash over a key slice ------------
// grid 8*nspl*32: b=blk&7 (XCD), ks=(blk>>3)&(nspl-1), qg=blk>>(3+lgs).
// Block = 128 queries (4 waves x 32). Writes unnormalized O + row-sums l.
// qb is NOT applied (2^qb factor cancels in O/l); row-sums via mfma-ones.
__global__ __launch_bounds__(256) void attn_split(
    const __hip_bfloat16* __restrict__ x,
    const __hip_bfloat16* __restrict__ y,
    const float* __restrict__ qb, const float* __restrict__ kb,
    const __hip_bfloat16* __restrict__ xT,
    float* __restrict__ Opart, float* __restrict__ lpart, int lgs) {
  __shared__ __hip_bfloat16 xs[2][32 * 72];    // 9.2 KB (X tile, tau-permuted)
  __shared__ __hip_bfloat16 vsm[2][64 * 40];   // 10.2 KB (V tile [d][key])
  const int tid = threadIdx.x;
  const int wv = tid >> 6, lane = tid & 63;
  const int l32 = lane & 31, hi = lane >> 5;
  const int b = blockIdx.x & 7;
  const int nspl = 1 << lgs;
  const int ks = (blockIdx.x >> 3) & (nspl - 1);
  const int qg = blockIdx.x >> (3 + lgs);
  const int kspl = SS >> lgs;
  const int koff = ks * kspl;
  const size_t rowq = ((size_t)b << 12) + (size_t)qg * 128 + wv * 32;

  // Y frags (B-operand of S^T): lane needs Y[q=l32][d=16mi+8hi+j]
  bf16x8 Y[4];
#pragma unroll
  for (int mi = 0; mi < 4; ++mi)
    Y[mi] = *(const bf16x8*)(y + (rowq + l32) * DD + mi * 16 + hi * 8);

  // staging: key sxr -> LDS row tau(sxr); V: [d][key] rows of 40
  const int sxr = tid >> 3, sxc = (tid & 7) * 8;
  const int g = sxr >> 2;
  const int taur = (sxr & 3) + 4 * ((g & 4) | ((g & 1) << 1) | ((g >> 1) & 1));
  const int svd = tid >> 2, svc = (tid & 3) * 8;
  const __hip_bfloat16* gx = x + ((size_t)b * SS + koff + sxr) * DD + sxc;
  const __hip_bfloat16* gv = xT + ((size_t)b * DD + svd) * SS + koff + svc;
  const float* kbp = kb + (size_t)b * SS + koff + hi * 8;

  // prologue: tile 0 -> buf 0; tile 1 -> regs
  bf16x8 nx = *(const bf16x8*)gx;
  bf16x8 nv = *(const bf16x8*)gv;
  *(bf16x8*)(&xs[0][taur * 72 + sxc]) = nx;
  *(bf16x8*)(&vsm[0][svd * 40 + svc]) = nv;
  nx = *(const bf16x8*)(gx + 32 * DD);
  nv = *(const bf16x8*)(gv + 32);
  __syncthreads();

  bf16x8 onesb;
#pragma unroll
  for (int j = 0; j < 8; ++j) onesb[j] = (__bf16)1.0f;

  f32x16 O0, O1, Ol;
#pragma unroll
  for (int r = 0; r < 16; ++r) { O0[r] = 0.f; O1[r] = 0.f; Ol[r] = 0.f; }

  for (int kt = 0; kt < kspl; kt += 32) {
    const int p = (kt >> 5) & 1, np = p ^ 1;
    if (kt + 32 < kspl) {
      *(bf16x8*)(&xs[np][taur * 72 + sxc]) = nx;
      *(bf16x8*)(&vsm[np][svd * 40 + svc]) = nv;
      if (kt + 64 < kspl) {
        nx = *(const bf16x8*)(gx + (size_t)(kt + 64) * DD);
        nv = *(const bf16x8*)(gv + (kt + 64));
      }
    }
    // kb for this tile (L2): reg r <-> key 8hi+(r&7)+16(r>>3)
    const f32x4 kb0a = *(const f32x4*)(kbp + kt);
    const f32x4 kb0b = *(const f32x4*)(kbp + kt + 4);
    const f32x4 kb1a = *(const f32x4*)(kbp + kt + 16);
    const f32x4 kb1b = *(const f32x4*)(kbp + kt + 20);

    // X A-frags: row l32 (tau-permuted keys), cols 16mi+8hi+j
    const bf16x8 A0 = *(const bf16x8*)(&xs[p][l32 * 72 + hi * 8]);
    const bf16x8 A1 = *(const bf16x8*)(&xs[p][l32 * 72 + 16 + hi * 8]);
    const bf16x8 A2 = *(const bf16x8*)(&xs[p][l32 * 72 + 32 + hi * 8]);
    const bf16x8 A3 = *(const bf16x8*)(&xs[p][l32 * 72 + 48 + hi * 8]);

    f32x16 S;
#pragma unroll
    for (int r = 0; r < 16; ++r) S[r] = 0.f;
    S = mfma32(A0, Y[0], S);
    S = mfma32(A1, Y[1], S);
    S = mfma32(A2, Y[2], S);
    S = mfma32(A3, Y[3], S);

    float pv[16];
#pragma unroll
    for (int r = 0; r < 16; ++r) {
      const float kv = (r < 4) ? kb0a[r & 3]
                     : (r < 8) ? kb0b[r & 3]
                     : (r < 12) ? kb1a[r & 3] : kb1b[r & 3];
      pv[r] = __builtin_amdgcn_exp2f(fmaf(S[r], CSCALE, kv));
    }
    // PV A-frags: C-reg order IS operand order (tau construction)
    u32x4 R0, R1;
    R0[0] = pack2(pv[0], pv[1]);  R0[1] = pack2(pv[2], pv[3]);
    R0[2] = pack2(pv[4], pv[5]);  R0[3] = pack2(pv[6], pv[7]);
    R1[0] = pack2(pv[8], pv[9]);  R1[1] = pack2(pv[10], pv[11]);
    R1[2] = pack2(pv[12], pv[13]); R1[3] = pack2(pv[14], pv[15]);
    bf16x8 Pf0, Pf1;
    __builtin_memcpy(&Pf0, &R0, 16);
    __builtin_memcpy(&Pf1, &R1, 16);

    // V B-frags: col d = l32+32md, rows keys 16mk+8hi+j
    const bf16x8 V00 = *(const bf16x8*)(&vsm[p][l32 * 40 + hi * 8]);
    const bf16x8 V10 = *(const bf16x8*)(&vsm[p][l32 * 40 + 16 + hi * 8]);
    const bf16x8 V01 = *(const bf16x8*)(&vsm[p][(l32 + 32) * 40 + hi * 8]);
    const bf16x8 V11 = *(const bf16x8*)(&vsm[p][(l32 + 32) * 40 + 16 + hi * 8]);

    O0 = mfma32(Pf0, V00, O0);
    O0 = mfma32(Pf1, V10, O0);
    O1 = mfma32(Pf0, V01, O1);
    O1 = mfma32(Pf1, V11, O1);
    Ol = mfma32(Pf0, onesb, Ol);   // row-sums (matrix pipe, not VALU)
    Ol = mfma32(Pf1, onesb, Ol);

    __syncthreads();
  }

  const size_t NP = (size_t)SS * 8;
  // lpart: Ol[r] = rowsum for query (r&3)+8(r>>2)+4hi (all l32 identical)
  if (l32 == 0) {
#pragma unroll
    for (int r = 0; r < 16; ++r)
      lpart[(size_t)ks * NP + rowq + (r & 3) + 8 * (r >> 2) + 4 * hi] = Ol[r];
  }

  // O write: lane = d-col (l32 + 32md), reg = query (r&3)+8*(r>>2)+4hi
  float* Op = Opart + ((size_t)ks * NP + rowq) * 64;
#pragma unroll
  for (int r = 0; r < 16; ++r) {
    const int qrow = (r & 3) + 8 * (r >> 2) + 4 * hi;
    Op[(size_t)qrow * 64 + l32]      = O0[r];
    Op[(size_t)qrow * 64 + 32 + l32] = O1[r];
  }
}

// ---------------- combine: merge once into LDS, 4-wave out-projection ------
// grid 1024 x 256: bb=blk&7 (writer XCD), gg=blk>>3 (32-query group).
// Partials read ONCE.
__global__ __launch_bounds__(256) void combine_kernel(
    const float* __restrict__ Opart, const float* __restrict__ lpart,
    const __hip_bfloat16* __restrict__ wvT, const void* __restrict__ bv_raw,
    void* __restrict__ out_raw, const int* __restrict__ flag, int nspl) {
  __shared__ __hip_bfloat16 pa[32 * 72];   // merged+normalized P (bf16)
  __shared__ float lsI[32];
  const int tid = threadIdx.x;
  const int bb = blockIdx.x & 7;
  const int gg = blockIdx.x >> 3;                // 0..127 within batch
  const size_t q0 = ((size_t)bb << 12) + (size_t)gg * 32;
  const int isF32 = *flag;
  const size_t NP = (size_t)SS * 8;

  if (tid < 32) {
    float ls = 0.f;
    for (int s = 0; s < nspl; ++s) ls += lpart[(size_t)s * NP + q0 + tid];
    lsI[tid] = (ls > 0.f) ? 1.0f / ls : 0.f;
  }
  // merge: thread handles query mq = tid>>3, d-seg md = (tid&7)*8
  const int mq = tid >> 3, md = (tid & 7) * 8;
  float acc[8];
#pragma unroll
  for (int j = 0; j < 8; ++j) acc[j] = 0.f;
  for (int s = 0; s < nspl; ++s) {
    const float* pp = Opart + ((size_t)s * NP + q0 + mq) * 64 + md;
    const float4 a = *(const float4*)pp;
    const float4 c = *(const float4*)(pp + 4);
    acc[0] += a.x; acc[1] += a.y; acc[2] += a.z; acc[3] += a.w;
    acc[4] += c.x; acc[5] += c.y; acc[6] += c.z; acc[7] += c.w;
  }
  __syncthreads();            // lsI ready
  {
    const float linv = lsI[mq];
    u32x4 R;
#pragma unroll
    for (int j = 0; j < 4; ++j)
      R[j] = pack2(acc[2*j] * linv, acc[2*j+1] * linv);
    __builtin_memcpy(&pa[mq * 72 + md], &R, 16);
  }
  __syncthreads();            // pa ready

  // out-proj: wave wv -> q-half (wv&1), h-half (wv>>1); 16 ht tiles each
  const int wv = tid >> 6, lane = tid & 63;
  const int l16 = lane & 15, quad = lane >> 4;
  const int qh = wv & 1, hh = wv >> 1;
  const __hip_bfloat16* par = &pa[(qh * 16 + l16) * 72];
  const bf16x8 Alo = *(const bf16x8*)(par + quad * 8);
  const bf16x8 Ahi = *(const bf16x8*)(par + 32 + quad * 8);

  float* outf = (float*)out_raw;
  __hip_bfloat16* outb = (__hip_bfloat16*)out_raw;
  const int ht0 = hh * 16;
#pragma unroll 4
  for (int ht = ht0; ht < ht0 + 16; ++ht) {
    const __hip_bfloat16* wp = wvT + (size_t)(ht * 16 + l16) * DD + quad * 8;
    const bf16x8 Wlo = *(const bf16x8*)wp;
    const bf16x8 Whi = *(const bf16x8*)(wp + 32);
    f32x4 C = (f32x4){0.f, 0.f, 0.f, 0.f};
    C = mfma16(Alo, Wlo, C);
    C = mfma16(Ahi, Whi, C);
    const float bvv = loadf(bv_raw, ht * 16 + l16, isF32);
#pragma unroll
    for (int r = 0; r < 4; ++r) {
      const size_t oidx = (q0 + qh * 16 + quad * 4 + r) * HH + ht * 16 + l16;
      const float val = C[r] + bvv;
      if (isF32) outf[oidx] = val;
      else       outb[oidx] = __float2bfloat16(val);
    }
  }
}

// ---------------- attn: R10 fallback (single pass, used if ws too small) ---
__global__ __launch_bounds__(256) void attn_kernel(
    const __hip_bfloat16* __restrict__ x,
    const __hip_bfloat16* __restrict__ y,
    const float* __restrict__ qb, const float* __restrict__ kb,
    const __hip_bfloat16* __restrict__ xT,
    const __hip_bfloat16* __restrict__ wvT,
    const void* __restrict__ bv_raw,
    void* __restrict__ out_raw, const int* __restrict__ flag) {
  __shared__ __hip_bfloat16 xs[2][32 * 72];
  __shared__ __hip_bfloat16 vsm[2][64 * 40];
  __shared__ float kbl[SS];
  const int tid = threadIdx.x;
  const int wv = tid >> 6, lane = tid & 63;
  const int l16 = lane & 15, quad = lane >> 4;
  const int b = blockIdx.x & 7;
  const int qt = (blockIdx.x >> 3) * 4 + wv;
  const size_t rowq = ((size_t)b << 12) + ((size_t)qt << 4);
  const int isF32 = *flag;

  const __hip_bfloat16* xb  = x  + ((size_t)b * SS) * DD;
  const __hip_bfloat16* xTb = xT + ((size_t)b * DD) * SS;
  const float* kbb = kb + ((size_t)b * SS);

  const __hip_bfloat16* yp = y + (rowq + l16) * DD + quad * 8;
  const bf16x8 Ylo = *(const bf16x8*)yp;
  const bf16x8 Yhi = *(const bf16x8*)(yp + 32);
  const float qbl = qb[rowq + l16];

  const int sxr = tid >> 3, sxc = (tid & 7) * 8;
  const int taur = (sxr & 3) + ((sxr >> 3) << 2) + (((sxr >> 2) & 1) << 4);
  const int svd = tid >> 2, svc = (tid & 3) * 8;
  const __hip_bfloat16* gx = xb + (size_t)sxr * DD + sxc;
  const __hip_bfloat16* gv = xTb + (size_t)svd * SS + svc;

#pragma unroll
  for (int j = 0; j < 4; ++j) {
    const int c = j * 256 + tid;
    *(f32x4*)(&kbl[c * 4]) = *(const f32x4*)(kbb + c * 4);
  }

  bf16x8 nx = *(const bf16x8*)gx;
  bf16x8 nv = *(const bf16x8*)gv;
  *(bf16x8*)(&xs[0][taur * 72 + sxc]) = nx;
  *(bf16x8*)(&vsm[0][svd * 40 + svc]) = nv;
  nx = *(const bf16x8*)(gx + 32 * DD);
  nv = *(const bf16x8*)(gv + 32);
  __syncthreads();

  bf16x8 onesb;
#pragma unroll
  for (int j = 0; j < 8; ++j) onesb[j] = (__bf16)1.0f;

  f32x4 O[4];
#pragma unroll
  for (int n = 0; n < 4; ++n) O[n] = (f32x4){0.f, 0.f, 0.f, 0.f};
  f32x4 Ol = (f32x4){0.f, 0.f, 0.f, 0.f};

  for (int kt = 0; kt < SS; kt += 32) {
    const int p = (kt >> 5) & 1, np = p ^ 1;
    if (kt + 32 < SS) {
      *(bf16x8*)(&xs[np][taur * 72 + sxc]) = nx;
      *(bf16x8*)(&vsm[np][svd * 40 + svc]) = nv;
      if (kt + 64 < SS) {
        nx = *(const bf16x8*)(gx + (size_t)(kt + 64) * DD);
        nv = *(const bf16x8*)(gv + (kt + 64));
      }
    }
    const bf16x8 B00 = *(const bf16x8*)(&xs[p][l16 * 72 + quad * 8]);
    const bf16x8 B01 = *(const bf16x8*)(&xs[p][l16 * 72 + 32 + quad * 8]);
    const bf16x8 B10 = *(const bf16x8*)(&xs[p][(16 + l16) * 72 + quad * 8]);
    const bf16x8 B11 = *(const bf16x8*)(&xs[p][(16 + l16) * 72 + 32 + quad * 8]);
    const bf16x8 V0 = *(const bf16x8*)(&vsm[p][l16 * 40 + quad * 8]);
    const bf16x8 V1 = *(const bf16x8*)(&vsm[p][(16 + l16) * 40 + quad * 8]);
    const bf16x8 V2 = *(const bf16x8*)(&vsm[p][(32 + l16) * 40 + quad * 8]);
    const bf16x8 V3 = *(const bf16x8*)(&vsm[p][(48 + l16) * 40 + quad * 8]);

    f32x4 S0 = (f32x4){0.f, 0.f, 0.f, 0.f};
    f32x4 S1 = (f32x4){0.f, 0.f, 0.f, 0.f};
    S0 = mfma16(B00, Ylo, S0);
    S0 = mfma16(B01, Yhi, S0);
    S1 = mfma16(B10, Ylo, S1);
    S1 = mfma16(B11, Yhi, S1);

    const f32x4 kb0 = *(const f32x4*)(&kbl[kt + quad * 8]);
    const f32x4 kb1 = *(const f32x4*)(&kbl[kt + quad * 8 + 4]);

    float p0[4], p1[4];
#pragma unroll
    for (int r = 0; r < 4; ++r) {
      p0[r] = __builtin_amdgcn_exp2f(fmaf(S0[r], CSCALE, qbl + kb0[r]));
      p1[r] = __builtin_amdgcn_exp2f(fmaf(S1[r], CSCALE, qbl + kb1[r]));
    }
    u32x4 R;
    R[0] = pack2(p0[0], p0[1]);
    R[1] = pack2(p0[2], p0[3]);
    R[2] = pack2(p1[0], p1[1]);
    R[3] = pack2(p1[2], p1[3]);
    bf16x8 Pf;
    __builtin_memcpy(&Pf, &R, 16);

    O[0] = mfma16(Pf, V0, O[0]);
    O[1] = mfma16(Pf, V1, O[1]);
    O[2] = mfma16(Pf, V2, O[2]);
    O[3] = mfma16(Pf, V3, O[3]);
    Ol = mfma16(Pf, onesb, Ol);

    __syncthreads();
  }

  float inv_l[4];
#pragma unroll
  for (int r = 0; r < 4; ++r)
    inv_l[r] = (Ol[r] > 0.f) ? 1.0f / Ol[r] : 0.f;
  __hip_bfloat16* pl = &xs[0][0] + wv * 1152;
#pragma unroll
  for (int n = 0; n < 4; ++n)
#pragma unroll
    for (int r = 0; r < 4; ++r) {
      const int row = quad * 4 + r;
      pl[row * 72 + n * 16 + l16] = __float2bfloat16(O[n][r] * inv_l[r]);
    }
  __syncthreads();
  const bf16x8 Alo = *(const bf16x8*)(pl + l16 * 72 + quad * 8);
  const bf16x8 Ahi = *(const bf16x8*)(pl + l16 * 72 + 32 + quad * 8);

  float* outf = (float*)out_raw;
  __hip_bfloat16* outb = (__hip_bfloat16*)out_raw;
#pragma unroll 4
  for (int ht = 0; ht < 32; ++ht) {
    const __hip_bfloat16* wp = wvT + (size_t)(ht * 16 + l16) * DD + quad * 8;
    const bf16x8 Wlo = *(const bf16x8*)wp;
    const bf16x8 Whi = *(const bf16x8*)(wp + 32);
    f32x4 C = (f32x4){0.f, 0.f, 0.f, 0.f};
    C = mfma16(Alo, Wlo, C);
    C = mfma16(Ahi, Whi, C);
    const float bvv = loadf(bv_raw, ht * 16 + l16, isF32);
#pragma unroll
    for (int r = 0; r < 4; ++r) {
      const size_t oidx = (rowq + quad * 4 + r) * HH + ht * 16 + l16;
      const float val = C[r] + bvv;
      if (isF32) outf[oidx] = val;
      else       outb[oidx] = __float2bfloat16(val);
    }
  }
}

// ---------------- launcher --------------------------------------------------
extern "C" void kernel_launch(void* const* d_in, const int* in_sizes, int n_in,
                              void* d_out, int out_size, void* d_ws,
                              size_t ws_size, hipStream_t stream) {
  char* ws = (char*)d_ws;
  int*   flag = (int*)(ws + 0);
  __hip_bfloat16* MT = (__hip_bfloat16*)(ws + 1024);       // 8 KB
  float* u    = (float*)(ws + 9216);
  float* w_   = (float*)(ws + 9728);
  float* c_   = (float*)(ws + 10240);
  __hip_bfloat16* wvT = (__hip_bfloat16*)(ws + 32768);     // 64 KB
  __hip_bfloat16* xc  = (__hip_bfloat16*)(ws + 131072);    // 4 MB
  __hip_bfloat16* y   = (__hip_bfloat16*)(ws + 4325376);   // 4 MB
  float* qb = (float*)(ws + 8519680);                       // 128 KB
  float* kb = (float*)(ws + 8650752);                       // 128 KB
  __hip_bfloat16* xT = (__hip_bfloat16*)(ws + 8781824);    // 4 MB
  float* Opart = (float*)(ws + 16777216);                   // up to 67 MB
  const size_t NP = (size_t)SS * 8;
  const size_t need8 = 16777216UL + 8UL * NP * 64 * 4 + 8UL * NP * 4;  // ~84.9 MB
  const size_t need4 = 16777216UL + 4UL * NP * 64 * 4 + 4UL * NP * 4;  // ~50.9 MB
  const size_t need2 = 16777216UL + 2UL * NP * 64 * 4 + 2UL * NP * 4;  // ~33.8 MB

  prep_kernel<<<81, 256, 0, stream>>>(d_in[1], d_in[3], d_in[5], d_in[2],
                                      d_in[4], MT, u, w_, c_, wvT, flag);
  proj_kernel<<<512, 256, 0, stream>>>(d_in[0], MT, u, w_, c_, xc, y, qb, kb,
                                       xT, flag);
  if (ws_size >= need8) {
    float* lpart = (float*)(ws + 16777216 + 8UL * NP * 64 * 4);
    attn_split<<<2048, 256, 0, stream>>>(xc, y, qb, kb, xT, Opart, lpart, 3);
    combine_kernel<<<1024, 256, 0, stream>>>(Opart, lpart, wvT, d_in[6], d_out,
                                             flag, 8);
  } else if (ws_size >= need4) {
    float* lpart = (float*)(ws + 16777216 + 4UL * NP * 64 * 4);
    attn_split<<<1024, 256, 0, stream>>>(xc, y, qb, kb, xT, Opart, lpart, 2);
    combine_kernel<<<1024, 256, 0, stream>>>(Opart, lpart, wvT, d_in[6], d_out,
                                             flag, 4);
  } else if (ws_size >= need2) {
    float* lpart = (float*)(ws + 16777216 + 2UL * NP * 64 * 4);
    attn_split<<<512, 256, 0, stream>>>(xc, y, qb, kb, xT, Opart, lpart, 1);
    combine_kernel<<<1024, 256, 0, stream>>>(Opart, lpart, wvT, d_in[6], d_out,
                                             flag, 2);
  } else {
    attn_kernel<<<512, 256, 0, stream>>>(xc, y, qb, kb, xT, wvT, d_in[6],
                                         d_out, flag);
  }
}